// Round 3
// baseline (301.857 us; speedup 1.0000x reference)
//
#include <hip/hip_runtime.h>
#include <math.h>

#define NB 32
#define NR 512
#define NT 128

typedef __attribute__((ext_vector_type(8))) short short8;
typedef __attribute__((ext_vector_type(4))) float f32x4;

// ---------------- wave (64-lane) reductions ----------------
__device__ __forceinline__ float wred_max(float v){
#pragma unroll
  for (int o = 32; o > 0; o >>= 1) v = fmaxf(v, __shfl_xor(v, o));
  return v;
}
__device__ __forceinline__ float wred_sum(float v){
#pragma unroll
  for (int o = 32; o > 0; o >>= 1) v += __shfl_xor(v, o);
  return v;
}

// ---------------- encoder kernel (unchanged) ----------------
__global__ __launch_bounds__(256) void enc_kernel(
    const float* __restrict__ rs, const float* __restrict__ ts,
    const float* __restrict__ r_w1, const float* __restrict__ r_b1,
    const float* __restrict__ r_w2, const float* __restrict__ r_b2,
    const float* __restrict__ t_w1, const float* __restrict__ t_b1,
    const float* __restrict__ t_w2, const float* __restrict__ t_b2,
    const float* __restrict__ wq, const float* __restrict__ bq,
    const float* __restrict__ wk, const float* __restrict__ bk,
    const float* __restrict__ wv, const float* __restrict__ bv,
    const float* __restrict__ a_w1,
    float* __restrict__ kbuf, float* __restrict__ vbuf,
    float* __restrict__ rpbuf, float* __restrict__ qbuf)
{
  __shared__ float w1s[448];
  __shared__ float wss[4096];
  __shared__ float h_s[64 * 66];
  __shared__ float rf_s[64 * 66];

  const int tid = threadIdx.x;
  const int rb = tid >> 2, t4 = tid & 3;
  const int blk = blockIdx.x;
  const bool robot = blk < 256;

  if (robot) {
    if (tid < 112) ((float4*)w1s)[tid] = ((const float4*)r_w1)[tid];
#pragma unroll
    for (int c = 0; c < 4; ++c)
      ((float4*)wss)[c * 256 + tid] = ((const float4*)r_w2)[c * 256 + tid];
  } else {
    if (tid < 96) ((float4*)w1s)[tid] = ((const float4*)t_w1)[tid];
#pragma unroll
    for (int c = 0; c < 4; ++c)
      ((float4*)wss)[c * 256 + tid] = ((const float4*)t_w2)[c * 256 + tid];
  }

  int g, K1;
  const float* xin; const float* b1; const float* b2;
  if (robot) { g = blk * 64 + rb;        K1 = 7; xin = rs + (size_t)g * 7; b1 = r_b1; b2 = r_b2; }
  else       { g = (blk - 256) * 64 + rb; K1 = 6; xin = ts + (size_t)g * 6; b1 = t_b1; b2 = t_b2; }

  float x[7];
  for (int k = 0; k < K1; ++k) x[k] = xin[k];
  __syncthreads();

  {
    float acc[16];
#pragma unroll
    for (int jj = 0; jj < 16; ++jj) acc[jj] = b1[t4 * 16 + jj];
    for (int k = 0; k < K1; ++k) {
      float xv = x[k];
#pragma unroll
      for (int jj = 0; jj < 16; ++jj) acc[jj] += xv * w1s[k * 64 + t4 * 16 + jj];
    }
#pragma unroll
    for (int jj = 0; jj < 16; ++jj) h_s[rb * 66 + t4 * 16 + jj] = fmaxf(acc[jj], 0.f);
  }
  __syncthreads();

  {
    float acc[16];
#pragma unroll
    for (int jj = 0; jj < 16; ++jj) acc[jj] = b2[t4 * 16 + jj];
    for (int k = 0; k < 64; ++k) {
      float hv = h_s[rb * 66 + k];
      const float4* wr = (const float4*)(wss + k * 64 + t4 * 16);
#pragma unroll
      for (int j4 = 0; j4 < 4; ++j4) {
        float4 w = wr[j4];
        acc[j4 * 4 + 0] += hv * w.x; acc[j4 * 4 + 1] += hv * w.y;
        acc[j4 * 4 + 2] += hv * w.z; acc[j4 * 4 + 3] += hv * w.w;
      }
    }
#pragma unroll
    for (int jj = 0; jj < 16; ++jj) rf_s[rb * 66 + t4 * 16 + jj] = fmaxf(acc[jj], 0.f);
  }

  const float* wp[3]; const float* bp[3]; float* op[3]; int npass;
  if (robot) {
    wp[0] = wk; bp[0] = bk;      op[0] = kbuf;
    wp[1] = wv; bp[1] = bv;      op[1] = vbuf;
    wp[2] = a_w1 + 64 * 64; bp[2] = nullptr; op[2] = rpbuf;
    npass = 3;
  } else {
    wp[0] = wq; bp[0] = bq; op[0] = qbuf; npass = 1;
  }
  for (int p = 0; p < npass; ++p) {
    __syncthreads();
#pragma unroll
    for (int c = 0; c < 4; ++c)
      ((float4*)wss)[c * 256 + tid] = ((const float4*)wp[p])[c * 256 + tid];
    __syncthreads();
    float acc[16];
#pragma unroll
    for (int jj = 0; jj < 16; ++jj) acc[jj] = bp[p] ? bp[p][t4 * 16 + jj] : 0.f;
    for (int k = 0; k < 64; ++k) {
      float hv = rf_s[rb * 66 + k];
      const float4* wr = (const float4*)(wss + k * 64 + t4 * 16);
#pragma unroll
      for (int j4 = 0; j4 < 4; ++j4) {
        float4 w = wr[j4];
        acc[j4 * 4 + 0] += hv * w.x; acc[j4 * 4 + 1] += hv * w.y;
        acc[j4 * 4 + 2] += hv * w.z; acc[j4 * 4 + 3] += hv * w.w;
      }
    }
    float4* o4 = (float4*)(op[p] + (size_t)g * 64 + t4 * 16);
#pragma unroll
    for (int j4 = 0; j4 < 4; ++j4)
      o4[j4] = make_float4(acc[j4 * 4 + 0], acc[j4 * 4 + 1], acc[j4 * 4 + 2], acc[j4 * 4 + 3]);
  }
}

// ---------------- attention kernel (lg stride 516, qs/tf union, unroll) ----
#define LGS 516
__global__ __launch_bounds__(256) void attn_kernel(
    const float* __restrict__ qbuf, const float* __restrict__ kbuf,
    const float* __restrict__ vbuf,
    const float* __restrict__ wo, const float* __restrict__ bo,
    const float* __restrict__ a_w1, const float* __restrict__ a_b1,
    float* __restrict__ tpbuf)
{
  __shared__ float qt_s[4 * 64];        // qs in phase A, tf in phase D
  __shared__ float lg[4][4 * LGS];      // [task][head*LGS + r]
  __shared__ float inv_s[16];
  __shared__ float cp[4][4 * 64];
  __shared__ float ctx_s[4 * 64];

  const int tid = threadIdx.x;
  const int jj = blockIdx.x & 31;
  const int b  = (jj & 7) * 4 + (jj >> 3);
  const int t0 = (blockIdx.x >> 5) * 4;

  if (tid < 64) {
    int tt = tid >> 4, i4 = tid & 15;
    float4 v = ((const float4*)(qbuf + (size_t)(b * NT + t0 + tt) * 64))[i4];
    v.x *= 0.25f; v.y *= 0.25f; v.z *= 0.25f; v.w *= 0.25f;
    ((float4*)qt_s)[tid] = v;
  }
  __syncthreads();

  // phase A: logits
  for (int rr = 0; rr < 2; ++rr) {
    int r = rr * 256 + tid;
    const float4* k4 = (const float4*)(kbuf + (size_t)(b * NR + r) * 64);
    float4 kk[16];
#pragma unroll
    for (int i = 0; i < 16; ++i) kk[i] = k4[i];
#pragma unroll
    for (int tt = 0; tt < 4; ++tt) {
      const float4* q4 = (const float4*)(qt_s + tt * 64);
#pragma unroll
      for (int h = 0; h < 4; ++h) {
        float s = 0.f;
#pragma unroll
        for (int i = 0; i < 4; ++i) {
          float4 qv = q4[h * 4 + i], kv = kk[h * 4 + i];
          s += qv.x * kv.x + qv.y * kv.y + qv.z * kv.z + qv.w * kv.w;
        }
        lg[tt][h * LGS + r] = s;
      }
    }
  }
  __syncthreads();

  // phase B: per-(task,head) softmax
  {
    int wid = tid >> 6, lane = tid & 63;
    for (int h = 0; h < 4; ++h) {
      float* row = &lg[wid][h * LGS];
      float v0[8];
#pragma unroll
      for (int u = 0; u < 8; ++u) v0[u] = row[u * 64 + lane];
      float m = v0[0];
#pragma unroll
      for (int u = 1; u < 8; ++u) m = fmaxf(m, v0[u]);
      m = wred_max(m);
      float s = 0.f;
#pragma unroll
      for (int u = 0; u < 8; ++u) {
        float e = expf(v0[u] - m);
        row[u * 64 + lane] = e;
        s += e;
      }
      s = wred_sum(s);
      if (lane == 0) inv_s[wid * 4 + h] = 1.f / s;
    }
  }
  __syncthreads();

  // phase C: ctx = p.v
  {
    int od = tid & 63, ch = tid >> 6;
    int h = od >> 4, d = od & 15;
    float acc[4] = {0.f, 0.f, 0.f, 0.f};
    const float* vptr = vbuf + (size_t)b * NR * 64 + h * 16 + d;
#pragma unroll 4
    for (int u = 0; u < 128; ++u) {
      int r = ch * 128 + u;
      float vv = vptr[(size_t)r * 64];
#pragma unroll
      for (int tt = 0; tt < 4; ++tt) acc[tt] += lg[tt][h * LGS + r] * vv;
    }
#pragma unroll
    for (int tt = 0; tt < 4; ++tt) cp[ch][tt * 64 + od] = acc[tt];
  }
  __syncthreads();
  {
    int tt = tid >> 6, od = tid & 63, h = od >> 4;
    ctx_s[tt * 64 + od] =
        (cp[0][tt * 64 + od] + cp[1][tt * 64 + od] +
         cp[2][tt * 64 + od] + cp[3][tt * 64 + od]) * inv_s[tt * 4 + h];
  }
  __syncthreads();

  // phase D: tf = ctx @ wo + bo  (tf goes into qt_s)
  {
    int jd = tid & 63, kc = tid >> 6;
    float p[4] = {0.f, 0.f, 0.f, 0.f};
    for (int k = 0; k < 16; ++k) {
      float w = wo[(kc * 16 + k) * 64 + jd];
#pragma unroll
      for (int tt = 0; tt < 4; ++tt) p[tt] += ctx_s[tt * 64 + kc * 16 + k] * w;
    }
#pragma unroll
    for (int tt = 0; tt < 4; ++tt) cp[kc][tt * 64 + jd] = p[tt];
  }
  __syncthreads();
  {
    int tt = tid >> 6, jd = tid & 63;
    qt_s[tt * 64 + jd] = cp[0][tt * 64 + jd] + cp[1][tt * 64 + jd] +
                         cp[2][tt * 64 + jd] + cp[3][tt * 64 + jd] + bo[jd];
  }
  __syncthreads();

  // tp = tf @ a_w1[:64] + a_b1
  {
    int jd = tid & 63, kc = tid >> 6;
    float p[4] = {0.f, 0.f, 0.f, 0.f};
    for (int k = 0; k < 16; ++k) {
      float w = a_w1[(kc * 16 + k) * 64 + jd];
#pragma unroll
      for (int tt = 0; tt < 4; ++tt) p[tt] += qt_s[tt * 64 + kc * 16 + k] * w;
    }
#pragma unroll
    for (int tt = 0; tt < 4; ++tt) cp[kc][tt * 64 + jd] = p[tt];
  }
  __syncthreads();
  {
    int tt = tid >> 6, jd = tid & 63;
    tpbuf[(size_t)(b * NT + t0 + tt) * 64 + jd] =
        cp[0][tt * 64 + jd] + cp[1][tt * 64 + jd] +
        cp[2][tt * 64 + jd] + cp[3][tt * 64 + jd] + a_b1[jd];
  }
}

// ---------------- prep: split W2 into hi/lo bf16 MFMA B-fragments ----------
// frag f = part*4 + kstep*2 + ntile; layout w2f[f][lane][8] ushort (16B/lane)
__global__ void prep_w2(const float* __restrict__ a_w2,
                        unsigned short* __restrict__ w2f)
{
  int l = threadIdx.x;               // 64 threads
  int n16 = l & 15, g = l >> 4;
  for (int f = 0; f < 8; ++f) {
    int ntile = f & 1, ks = (f >> 1) & 1, part = f >> 2;
    for (int j = 0; j < 8; ++j) {
      int k = ks * 32 + g * 8 + j;
      int n = ntile * 16 + n16;
      unsigned wb = __float_as_uint(a_w2[k * 32 + n]);
      unsigned hib = wb & 0xffff0000u;
      float lof = __uint_as_float(wb) - __uint_as_float(hib);
      unsigned lob = __float_as_uint(lof) & 0xffff0000u;
      w2f[((size_t)f * 64 + l) * 8 + j] =
          (unsigned short)((part == 0 ? hib : lob) >> 16);
    }
  }
}

// ---------------- pairwise allocation kernel (v3: split-bf16 MFMA) ---------
// One block per (b,t), 256 thr = 4 waves; wave handles 128 robots = 8 m-tiles.
// h1 = relu(tp+rp) generated per-lane in A-fragment layout
// (A[m=lane&15][k=(lane>>4)*8+j], m120-verified), split hi/lo bf16;
// h2 = h1 @ W2 via 4 MFMA passes (hi*hi+hi*lo+lo*hi+lo*lo) -> fp32-grade.
__device__ __forceinline__ void mk_frags(float4 ra, float4 rb,
                                         float4 ta, float4 tb,
                                         short8* Ah, short8* Al)
{
  float x0 = fmaxf(ra.x + ta.x, 0.f), x1 = fmaxf(ra.y + ta.y, 0.f);
  float x2 = fmaxf(ra.z + ta.z, 0.f), x3 = fmaxf(ra.w + ta.w, 0.f);
  float x4 = fmaxf(rb.x + tb.x, 0.f), x5 = fmaxf(rb.y + tb.y, 0.f);
  float x6 = fmaxf(rb.z + tb.z, 0.f), x7 = fmaxf(rb.w + tb.w, 0.f);
  unsigned u0 = __float_as_uint(x0), u1 = __float_as_uint(x1);
  unsigned u2 = __float_as_uint(x2), u3 = __float_as_uint(x3);
  unsigned u4 = __float_as_uint(x4), u5 = __float_as_uint(x5);
  unsigned u6 = __float_as_uint(x6), u7 = __float_as_uint(x7);
  unsigned m0 = __float_as_uint(x0 - __uint_as_float(u0 & 0xffff0000u));
  unsigned m1 = __float_as_uint(x1 - __uint_as_float(u1 & 0xffff0000u));
  unsigned m2 = __float_as_uint(x2 - __uint_as_float(u2 & 0xffff0000u));
  unsigned m3 = __float_as_uint(x3 - __uint_as_float(u3 & 0xffff0000u));
  unsigned m4 = __float_as_uint(x4 - __uint_as_float(u4 & 0xffff0000u));
  unsigned m5 = __float_as_uint(x5 - __uint_as_float(u5 & 0xffff0000u));
  unsigned m6 = __float_as_uint(x6 - __uint_as_float(u6 & 0xffff0000u));
  unsigned m7 = __float_as_uint(x7 - __uint_as_float(u7 & 0xffff0000u));
  int4 hi = make_int4((int)((u1 & 0xffff0000u) | (u0 >> 16)),
                      (int)((u3 & 0xffff0000u) | (u2 >> 16)),
                      (int)((u5 & 0xffff0000u) | (u4 >> 16)),
                      (int)((u7 & 0xffff0000u) | (u6 >> 16)));
  int4 lo = make_int4((int)((m1 & 0xffff0000u) | (m0 >> 16)),
                      (int)((m3 & 0xffff0000u) | (m2 >> 16)),
                      (int)((m5 & 0xffff0000u) | (m4 >> 16)),
                      (int)((m7 & 0xffff0000u) | (m6 >> 16)));
  *Ah = __builtin_bit_cast(short8, hi);
  *Al = __builtin_bit_cast(short8, lo);
}

__global__ __launch_bounds__(256) void pair_kernel(
    const float* __restrict__ tpbuf, const float* __restrict__ rpbuf,
    const unsigned short* __restrict__ w2f,
    const float* __restrict__ a_b2, const float* __restrict__ a_w3,
    float* __restrict__ out)
{
  __shared__ float scores_s[512];
  __shared__ float red_a[4];
  __shared__ float red_b[4];

  const int tid = threadIdx.x;
  const int jj = blockIdx.x & 31;
  const int b  = (jj & 7) * 4 + (jj >> 3);   // XCD-locality swizzle
  const int t  = blockIdx.x >> 5;
  const int wave = tid >> 6, lane = tid & 63;
  const int n16 = lane & 15, g = lane >> 4;

  // B fragments (8 x short8), lane-order precomputed -> coalesced 16B loads
  short8 B[8];
#pragma unroll
  for (int f = 0; f < 8; ++f)
    B[f] = __builtin_bit_cast(short8, ((const int4*)w2f)[f * 64 + lane]);

  // tp window: 16 floats (2 ksteps x 8), per-lane k slice
  const float* tp = tpbuf + (size_t)(b * NT + t) * 64;
  float4 tp0a = *(const float4*)(tp + g * 8);
  float4 tp0b = *(const float4*)(tp + g * 8 + 4);
  float4 tp1a = *(const float4*)(tp + 32 + g * 8);
  float4 tp1b = *(const float4*)(tp + 32 + g * 8 + 4);

  float b20 = a_b2[n16], b21 = a_b2[16 + n16];
  f32x4 acc[8][2];
#pragma unroll
  for (int mt = 0; mt < 8; ++mt) {
    acc[mt][0] = (f32x4){b20, b20, b20, b20};
    acc[mt][1] = (f32x4){b21, b21, b21, b21};
  }

  const float* rpb = rpbuf + (size_t)b * NR * 64;

#pragma unroll
  for (int mt = 0; mt < 8; ++mt) {
    const float* rp = rpb + (size_t)(wave * 128 + mt * 16 + n16) * 64 + g * 8;
    float4 ra0 = *(const float4*)(rp);
    float4 rb0 = *(const float4*)(rp + 4);
    float4 ra1 = *(const float4*)(rp + 32);
    float4 rb1 = *(const float4*)(rp + 36);
    short8 Ah0, Al0, Ah1, Al1;
    mk_frags(ra0, rb0, tp0a, tp0b, &Ah0, &Al0);
    mk_frags(ra1, rb1, tp1a, tp1b, &Ah1, &Al1);
#pragma unroll
    for (int nt = 0; nt < 2; ++nt) {
      f32x4 a = acc[mt][nt];
      a = __builtin_amdgcn_mfma_f32_16x16x32_bf16(Ah0, B[0 + nt],     a, 0, 0, 0);
      a = __builtin_amdgcn_mfma_f32_16x16x32_bf16(Ah0, B[4 + nt],     a, 0, 0, 0);
      a = __builtin_amdgcn_mfma_f32_16x16x32_bf16(Al0, B[0 + nt],     a, 0, 0, 0);
      a = __builtin_amdgcn_mfma_f32_16x16x32_bf16(Al0, B[4 + nt],     a, 0, 0, 0);
      a = __builtin_amdgcn_mfma_f32_16x16x32_bf16(Ah1, B[2 + nt],     a, 0, 0, 0);
      a = __builtin_amdgcn_mfma_f32_16x16x32_bf16(Ah1, B[6 + nt],     a, 0, 0, 0);
      a = __builtin_amdgcn_mfma_f32_16x16x32_bf16(Al1, B[2 + nt],     a, 0, 0, 0);
      a = __builtin_amdgcn_mfma_f32_16x16x32_bf16(Al1, B[6 + nt],     a, 0, 0, 0);
      acc[mt][nt] = a;
    }
  }

  // epilogue: score = relu(h2) . w3 (b3 omitted: softmax shift-invariant)
  float w30 = a_w3[n16], w31 = a_w3[16 + n16];
#pragma unroll
  for (int mt = 0; mt < 8; ++mt) {
#pragma unroll
    for (int reg = 0; reg < 4; ++reg) {
      float s = fmaxf(acc[mt][0][reg], 0.f) * w30 +
                fmaxf(acc[mt][1][reg], 0.f) * w31;
      s += __shfl_xor(s, 1);
      s += __shfl_xor(s, 2);
      s += __shfl_xor(s, 4);
      s += __shfl_xor(s, 8);
      if (n16 == 0) scores_s[wave * 128 + mt * 16 + g * 4 + reg] = s;
    }
  }
  __syncthreads();

  // block softmax over 512 scores (2 per thread)
  float s0 = scores_s[tid], s1 = scores_s[tid + 256];
  int l2 = tid & 63, wid = tid >> 6;
  float mw = wred_max(fmaxf(s0, s1));
  if (l2 == 0) red_a[wid] = mw;
  __syncthreads();
  float m = fmaxf(fmaxf(red_a[0], red_a[1]), fmaxf(red_a[2], red_a[3]));
  float e0 = expf(s0 - m), e1 = expf(s1 - m);
  float sw = wred_sum(e0 + e1);
  if (l2 == 0) red_b[wid] = sw;
  __syncthreads();
  float inv = 1.f / (red_b[0] + red_b[1] + red_b[2] + red_b[3]);

  float* op = out + (size_t)(b * NT + t) * NR;
  op[tid]       = e0 * inv;
  op[256 + tid] = e1 * inv;
}

// ---------------- launch ----------------
extern "C" void kernel_launch(void* const* d_in, const int* in_sizes, int n_in,
                              void* d_out, int out_size, void* d_ws, size_t ws_size,
                              hipStream_t stream)
{
  const float* rs   = (const float*)d_in[0];
  const float* ts   = (const float*)d_in[1];
  const float* r_w1 = (const float*)d_in[2];  const float* r_b1 = (const float*)d_in[3];
  const float* r_w2 = (const float*)d_in[4];  const float* r_b2 = (const float*)d_in[5];
  const float* t_w1 = (const float*)d_in[6];  const float* t_b1 = (const float*)d_in[7];
  const float* t_w2 = (const float*)d_in[8];  const float* t_b2 = (const float*)d_in[9];
  const float* wq   = (const float*)d_in[10]; const float* bq   = (const float*)d_in[11];
  const float* wk   = (const float*)d_in[12]; const float* bk   = (const float*)d_in[13];
  const float* wv   = (const float*)d_in[14]; const float* bv   = (const float*)d_in[15];
  const float* wo   = (const float*)d_in[16]; const float* bo   = (const float*)d_in[17];
  const float* a_w1 = (const float*)d_in[18]; const float* a_b1 = (const float*)d_in[19];
  const float* a_w2 = (const float*)d_in[20]; const float* a_b2 = (const float*)d_in[21];
  const float* a_w3 = (const float*)d_in[22]; const float* a_b3 = (const float*)d_in[23];

  float* wsf   = (float*)d_ws;
  float* kbuf  = wsf;                                   // 32*512*64
  float* vbuf  = kbuf  + (size_t)NB * NR * 64;          // 32*512*64
  float* rpbuf = vbuf  + (size_t)NB * NR * 64;          // 32*512*64
  float* qbuf  = rpbuf + (size_t)NB * NR * 64;          // 32*128*64
  float* tpbuf = qbuf  + (size_t)NB * NT * 64;          // 32*128*64
  unsigned short* w2f = (unsigned short*)(tpbuf + (size_t)NB * NT * 64); // 8*64*8

  prep_w2<<<dim3(1), dim3(64), 0, stream>>>(a_w2, w2f);

  enc_kernel<<<dim3(320), dim3(256), 0, stream>>>(
      rs, ts, r_w1, r_b1, r_w2, r_b2, t_w1, t_b1, t_w2, t_b2,
      wq, bq, wk, bk, wv, bv, a_w1, kbuf, vbuf, rpbuf, qbuf);

  attn_kernel<<<dim3(1024), dim3(256), 0, stream>>>(
      qbuf, kbuf, vbuf, wo, bo, a_w1, a_b1, tpbuf);

  pair_kernel<<<dim3(4096), dim3(256), 0, stream>>>(
      tpbuf, rpbuf, w2f, a_b2, a_w3, (float*)d_out);
}

// Round 4
// 262.624 us; speedup vs baseline: 1.1494x; 1.1494x over previous
//
#include <hip/hip_runtime.h>
#include <math.h>

#define NB 32
#define NR 512
#define NT 128

typedef __attribute__((ext_vector_type(8))) short short8;
typedef __attribute__((ext_vector_type(4))) float f32x4;

// ---------------- wave (64-lane) reductions ----------------
__device__ __forceinline__ float wred_max(float v){
#pragma unroll
  for (int o = 32; o > 0; o >>= 1) v = fmaxf(v, __shfl_xor(v, o));
  return v;
}
__device__ __forceinline__ float wred_sum(float v){
#pragma unroll
  for (int o = 32; o > 0; o >>= 1) v += __shfl_xor(v, o);
  return v;
}

// ---------------- encoder kernel (+ fused W2-frag prep in block 320) -------
__global__ __launch_bounds__(256) void enc_kernel(
    const float* __restrict__ rs, const float* __restrict__ ts,
    const float* __restrict__ r_w1, const float* __restrict__ r_b1,
    const float* __restrict__ r_w2, const float* __restrict__ r_b2,
    const float* __restrict__ t_w1, const float* __restrict__ t_b1,
    const float* __restrict__ t_w2, const float* __restrict__ t_b2,
    const float* __restrict__ wq, const float* __restrict__ bq,
    const float* __restrict__ wk, const float* __restrict__ bk,
    const float* __restrict__ wv, const float* __restrict__ bv,
    const float* __restrict__ a_w1, const float* __restrict__ a_w2,
    float* __restrict__ kbuf, float* __restrict__ vbuf,
    float* __restrict__ rpbuf, float* __restrict__ qbuf,
    unsigned short* __restrict__ w2f)
{
  __shared__ float w1s[448];
  __shared__ float wss[4096];
  __shared__ float h_s[64 * 66];
  __shared__ float rf_s[64 * 66];

  const int tid = threadIdx.x;
  const int blk = blockIdx.x;

  if (blk == 320) {        // fused prep: split a_w2 into hi/lo bf16 B-frags
    if (tid < 64) {
      int l = tid, n16 = l & 15, g = l >> 4;
      for (int f = 0; f < 8; ++f) {
        int ntile = f & 1, ks = (f >> 1) & 1, part = f >> 2;
        for (int j = 0; j < 8; ++j) {
          int k = ks * 32 + g * 8 + j;
          int n = ntile * 16 + n16;
          unsigned wb = __float_as_uint(a_w2[k * 32 + n]);
          unsigned hib = wb & 0xffff0000u;
          float lof = __uint_as_float(wb) - __uint_as_float(hib);
          unsigned lob = __float_as_uint(lof) & 0xffff0000u;
          w2f[((size_t)f * 64 + l) * 8 + j] =
              (unsigned short)((part == 0 ? hib : lob) >> 16);
        }
      }
    }
    return;
  }

  const int rb = tid >> 2, t4 = tid & 3;
  const bool robot = blk < 256;

  if (robot) {
    if (tid < 112) ((float4*)w1s)[tid] = ((const float4*)r_w1)[tid];
#pragma unroll
    for (int c = 0; c < 4; ++c)
      ((float4*)wss)[c * 256 + tid] = ((const float4*)r_w2)[c * 256 + tid];
  } else {
    if (tid < 96) ((float4*)w1s)[tid] = ((const float4*)t_w1)[tid];
#pragma unroll
    for (int c = 0; c < 4; ++c)
      ((float4*)wss)[c * 256 + tid] = ((const float4*)t_w2)[c * 256 + tid];
  }

  int g, K1;
  const float* xin; const float* b1; const float* b2;
  if (robot) { g = blk * 64 + rb;        K1 = 7; xin = rs + (size_t)g * 7; b1 = r_b1; b2 = r_b2; }
  else       { g = (blk - 256) * 64 + rb; K1 = 6; xin = ts + (size_t)g * 6; b1 = t_b1; b2 = t_b2; }

  float x[7];
  for (int k = 0; k < K1; ++k) x[k] = xin[k];
  __syncthreads();

  {
    float acc[16];
#pragma unroll
    for (int jj = 0; jj < 16; ++jj) acc[jj] = b1[t4 * 16 + jj];
    for (int k = 0; k < K1; ++k) {
      float xv = x[k];
#pragma unroll
      for (int jj = 0; jj < 16; ++jj) acc[jj] += xv * w1s[k * 64 + t4 * 16 + jj];
    }
#pragma unroll
    for (int jj = 0; jj < 16; ++jj) h_s[rb * 66 + t4 * 16 + jj] = fmaxf(acc[jj], 0.f);
  }
  __syncthreads();

  {
    float acc[16];
#pragma unroll
    for (int jj = 0; jj < 16; ++jj) acc[jj] = b2[t4 * 16 + jj];
    for (int k = 0; k < 64; ++k) {
      float hv = h_s[rb * 66 + k];
      const float4* wr = (const float4*)(wss + k * 64 + t4 * 16);
#pragma unroll
      for (int j4 = 0; j4 < 4; ++j4) {
        float4 w = wr[j4];
        acc[j4 * 4 + 0] += hv * w.x; acc[j4 * 4 + 1] += hv * w.y;
        acc[j4 * 4 + 2] += hv * w.z; acc[j4 * 4 + 3] += hv * w.w;
      }
    }
#pragma unroll
    for (int jj = 0; jj < 16; ++jj) rf_s[rb * 66 + t4 * 16 + jj] = fmaxf(acc[jj], 0.f);
  }

  const float* wp[3]; const float* bp[3]; float* op[3]; int npass;
  if (robot) {
    wp[0] = wk; bp[0] = bk;      op[0] = kbuf;
    wp[1] = wv; bp[1] = bv;      op[1] = vbuf;
    wp[2] = a_w1 + 64 * 64; bp[2] = nullptr; op[2] = rpbuf;
    npass = 3;
  } else {
    wp[0] = wq; bp[0] = bq; op[0] = qbuf; npass = 1;
  }
  for (int p = 0; p < npass; ++p) {
    __syncthreads();
#pragma unroll
    for (int c = 0; c < 4; ++c)
      ((float4*)wss)[c * 256 + tid] = ((const float4*)wp[p])[c * 256 + tid];
    __syncthreads();
    float acc[16];
#pragma unroll
    for (int jj = 0; jj < 16; ++jj) acc[jj] = bp[p] ? bp[p][t4 * 16 + jj] : 0.f;
    for (int k = 0; k < 64; ++k) {
      float hv = rf_s[rb * 66 + k];
      const float4* wr = (const float4*)(wss + k * 64 + t4 * 16);
#pragma unroll
      for (int j4 = 0; j4 < 4; ++j4) {
        float4 w = wr[j4];
        acc[j4 * 4 + 0] += hv * w.x; acc[j4 * 4 + 1] += hv * w.y;
        acc[j4 * 4 + 2] += hv * w.z; acc[j4 * 4 + 3] += hv * w.w;
      }
    }
    float4* o4 = (float4*)(op[p] + (size_t)g * 64 + t4 * 16);
#pragma unroll
    for (int j4 = 0; j4 < 4; ++j4)
      o4[j4] = make_float4(acc[j4 * 4 + 0], acc[j4 * 4 + 1], acc[j4 * 4 + 2], acc[j4 * 4 + 3]);
  }
}

// ---------------- attention kernel (unchanged from round 3) ----------------
#define LGS 516
__global__ __launch_bounds__(256) void attn_kernel(
    const float* __restrict__ qbuf, const float* __restrict__ kbuf,
    const float* __restrict__ vbuf,
    const float* __restrict__ wo, const float* __restrict__ bo,
    const float* __restrict__ a_w1, const float* __restrict__ a_b1,
    float* __restrict__ tpbuf)
{
  __shared__ float qt_s[4 * 64];
  __shared__ float lg[4][4 * LGS];
  __shared__ float inv_s[16];
  __shared__ float cp[4][4 * 64];
  __shared__ float ctx_s[4 * 64];

  const int tid = threadIdx.x;
  const int jj = blockIdx.x & 31;
  const int b  = (jj & 7) * 4 + (jj >> 3);
  const int t0 = (blockIdx.x >> 5) * 4;

  if (tid < 64) {
    int tt = tid >> 4, i4 = tid & 15;
    float4 v = ((const float4*)(qbuf + (size_t)(b * NT + t0 + tt) * 64))[i4];
    v.x *= 0.25f; v.y *= 0.25f; v.z *= 0.25f; v.w *= 0.25f;
    ((float4*)qt_s)[tid] = v;
  }
  __syncthreads();

  for (int rr = 0; rr < 2; ++rr) {
    int r = rr * 256 + tid;
    const float4* k4 = (const float4*)(kbuf + (size_t)(b * NR + r) * 64);
    float4 kk[16];
#pragma unroll
    for (int i = 0; i < 16; ++i) kk[i] = k4[i];
#pragma unroll
    for (int tt = 0; tt < 4; ++tt) {
      const float4* q4 = (const float4*)(qt_s + tt * 64);
#pragma unroll
      for (int h = 0; h < 4; ++h) {
        float s = 0.f;
#pragma unroll
        for (int i = 0; i < 4; ++i) {
          float4 qv = q4[h * 4 + i], kv = kk[h * 4 + i];
          s += qv.x * kv.x + qv.y * kv.y + qv.z * kv.z + qv.w * kv.w;
        }
        lg[tt][h * LGS + r] = s;
      }
    }
  }
  __syncthreads();

  {
    int wid = tid >> 6, lane = tid & 63;
    for (int h = 0; h < 4; ++h) {
      float* row = &lg[wid][h * LGS];
      float v0[8];
#pragma unroll
      for (int u = 0; u < 8; ++u) v0[u] = row[u * 64 + lane];
      float m = v0[0];
#pragma unroll
      for (int u = 1; u < 8; ++u) m = fmaxf(m, v0[u]);
      m = wred_max(m);
      float s = 0.f;
#pragma unroll
      for (int u = 0; u < 8; ++u) {
        float e = expf(v0[u] - m);
        row[u * 64 + lane] = e;
        s += e;
      }
      s = wred_sum(s);
      if (lane == 0) inv_s[wid * 4 + h] = 1.f / s;
    }
  }
  __syncthreads();

  {
    int od = tid & 63, ch = tid >> 6;
    int h = od >> 4, d = od & 15;
    float acc[4] = {0.f, 0.f, 0.f, 0.f};
    const float* vptr = vbuf + (size_t)b * NR * 64 + h * 16 + d;
#pragma unroll 4
    for (int u = 0; u < 128; ++u) {
      int r = ch * 128 + u;
      float vv = vptr[(size_t)r * 64];
#pragma unroll
      for (int tt = 0; tt < 4; ++tt) acc[tt] += lg[tt][h * LGS + r] * vv;
    }
#pragma unroll
    for (int tt = 0; tt < 4; ++tt) cp[ch][tt * 64 + od] = acc[tt];
  }
  __syncthreads();
  {
    int tt = tid >> 6, od = tid & 63, h = od >> 4;
    ctx_s[tt * 64 + od] =
        (cp[0][tt * 64 + od] + cp[1][tt * 64 + od] +
         cp[2][tt * 64 + od] + cp[3][tt * 64 + od]) * inv_s[tt * 4 + h];
  }
  __syncthreads();

  {
    int jd = tid & 63, kc = tid >> 6;
    float p[4] = {0.f, 0.f, 0.f, 0.f};
    for (int k = 0; k < 16; ++k) {
      float w = wo[(kc * 16 + k) * 64 + jd];
#pragma unroll
      for (int tt = 0; tt < 4; ++tt) p[tt] += ctx_s[tt * 64 + kc * 16 + k] * w;
    }
#pragma unroll
    for (int tt = 0; tt < 4; ++tt) cp[kc][tt * 64 + jd] = p[tt];
  }
  __syncthreads();
  {
    int tt = tid >> 6, jd = tid & 63;
    qt_s[tt * 64 + jd] = cp[0][tt * 64 + jd] + cp[1][tt * 64 + jd] +
                         cp[2][tt * 64 + jd] + cp[3][tt * 64 + jd] + bo[jd];
  }
  __syncthreads();

  {
    int jd = tid & 63, kc = tid >> 6;
    float p[4] = {0.f, 0.f, 0.f, 0.f};
    for (int k = 0; k < 16; ++k) {
      float w = a_w1[(kc * 16 + k) * 64 + jd];
#pragma unroll
      for (int tt = 0; tt < 4; ++tt) p[tt] += qt_s[tt * 64 + kc * 16 + k] * w;
    }
#pragma unroll
    for (int tt = 0; tt < 4; ++tt) cp[kc][tt * 64 + jd] = p[tt];
  }
  __syncthreads();
  {
    int tt = tid >> 6, jd = tid & 63;
    tpbuf[(size_t)(b * NT + t0 + tt) * 64 + jd] =
        cp[0][tt * 64 + jd] + cp[1][tt * 64 + jd] +
        cp[2][tt * 64 + jd] + cp[3][tt * 64 + jd] + a_b1[jd];
  }
}

// ---------------- pairwise allocation kernel (v4) --------------------------
// 2048 blocks = (b, task-pair); 4 waves; wave = 128 robots (8 m-tiles).
// Per mt: load rp ONCE, reuse for 2 tasks; per (task,nt): 6 MFMAs
// (hh,lh,hl per kstep; lo*lo dropped); epilogue folded per-mt so acc
// registers don't persist across the mt loop.
__device__ __forceinline__ void mk_frags(float4 ra, float4 rb,
                                         float4 ta, float4 tb,
                                         short8* Ah, short8* Al)
{
  float x0 = fmaxf(ra.x + ta.x, 0.f), x1 = fmaxf(ra.y + ta.y, 0.f);
  float x2 = fmaxf(ra.z + ta.z, 0.f), x3 = fmaxf(ra.w + ta.w, 0.f);
  float x4 = fmaxf(rb.x + tb.x, 0.f), x5 = fmaxf(rb.y + tb.y, 0.f);
  float x6 = fmaxf(rb.z + tb.z, 0.f), x7 = fmaxf(rb.w + tb.w, 0.f);
  unsigned u0 = __float_as_uint(x0), u1 = __float_as_uint(x1);
  unsigned u2 = __float_as_uint(x2), u3 = __float_as_uint(x3);
  unsigned u4 = __float_as_uint(x4), u5 = __float_as_uint(x5);
  unsigned u6 = __float_as_uint(x6), u7 = __float_as_uint(x7);
  unsigned m0 = __float_as_uint(x0 - __uint_as_float(u0 & 0xffff0000u));
  unsigned m1 = __float_as_uint(x1 - __uint_as_float(u1 & 0xffff0000u));
  unsigned m2 = __float_as_uint(x2 - __uint_as_float(u2 & 0xffff0000u));
  unsigned m3 = __float_as_uint(x3 - __uint_as_float(u3 & 0xffff0000u));
  unsigned m4 = __float_as_uint(x4 - __uint_as_float(u4 & 0xffff0000u));
  unsigned m5 = __float_as_uint(x5 - __uint_as_float(u5 & 0xffff0000u));
  unsigned m6 = __float_as_uint(x6 - __uint_as_float(u6 & 0xffff0000u));
  unsigned m7 = __float_as_uint(x7 - __uint_as_float(u7 & 0xffff0000u));
  int4 hi = make_int4((int)((u1 & 0xffff0000u) | (u0 >> 16)),
                      (int)((u3 & 0xffff0000u) | (u2 >> 16)),
                      (int)((u5 & 0xffff0000u) | (u4 >> 16)),
                      (int)((u7 & 0xffff0000u) | (u6 >> 16)));
  int4 lo = make_int4((int)((m1 & 0xffff0000u) | (m0 >> 16)),
                      (int)((m3 & 0xffff0000u) | (m2 >> 16)),
                      (int)((m5 & 0xffff0000u) | (m4 >> 16)),
                      (int)((m7 & 0xffff0000u) | (m6 >> 16)));
  *Ah = __builtin_bit_cast(short8, hi);
  *Al = __builtin_bit_cast(short8, lo);
}

__global__ __launch_bounds__(256) void pair_kernel(
    const float* __restrict__ tpbuf, const float* __restrict__ rpbuf,
    const unsigned short* __restrict__ w2f,
    const float* __restrict__ a_b2, const float* __restrict__ a_w3,
    float* __restrict__ out)
{
  __shared__ float scores_s[2][512];
  __shared__ float red_a[4];
  __shared__ float red_b[4];

  const int tid = threadIdx.x;
  const int jj = blockIdx.x & 31;
  const int b  = (jj & 7) * 4 + (jj >> 3);   // XCD-locality swizzle
  const int t2 = blockIdx.x >> 5;            // task pair [0,64)
  const int wave = tid >> 6, lane = tid & 63;
  const int n16 = lane & 15, g = lane >> 4;

  // B fragments (hi: 0-3, lo: 4-7), coalesced 16B loads
  short8 B[8];
#pragma unroll
  for (int f = 0; f < 8; ++f)
    B[f] = __builtin_bit_cast(short8, ((const int4*)w2f)[f * 64 + lane]);

  // tp slices for the 2 tasks
  const float* tpA = tpbuf + (size_t)(b * NT + t2 * 2) * 64 + g * 8;
  const float* tpB = tpA + 64;
  float4 tA0a = *(const float4*)(tpA),      tA0b = *(const float4*)(tpA + 4);
  float4 tA1a = *(const float4*)(tpA + 32), tA1b = *(const float4*)(tpA + 36);
  float4 tB0a = *(const float4*)(tpB),      tB0b = *(const float4*)(tpB + 4);
  float4 tB1a = *(const float4*)(tpB + 32), tB1b = *(const float4*)(tpB + 36);

  float b20 = a_b2[n16], b21 = a_b2[16 + n16];
  float w30 = a_w3[n16], w31 = a_w3[16 + n16];

  const float* rpb = rpbuf + (size_t)b * NR * 64 + g * 8;

#pragma unroll
  for (int mt = 0; mt < 8; ++mt) {
    const float* rp = rpb + (size_t)(wave * 128 + mt * 16 + n16) * 64;
    float4 ra0 = *(const float4*)(rp);
    float4 rb0 = *(const float4*)(rp + 4);
    float4 ra1 = *(const float4*)(rp + 32);
    float4 rb1 = *(const float4*)(rp + 36);

#pragma unroll
    for (int task = 0; task < 2; ++task) {
      short8 Ah0, Al0, Ah1, Al1;
      if (task == 0) {
        mk_frags(ra0, rb0, tA0a, tA0b, &Ah0, &Al0);
        mk_frags(ra1, rb1, tA1a, tA1b, &Ah1, &Al1);
      } else {
        mk_frags(ra0, rb0, tB0a, tB0b, &Ah0, &Al0);
        mk_frags(ra1, rb1, tB1a, tB1b, &Ah1, &Al1);
      }
      f32x4 acc0 = (f32x4){b20, b20, b20, b20};
      f32x4 acc1 = (f32x4){b21, b21, b21, b21};
      acc0 = __builtin_amdgcn_mfma_f32_16x16x32_bf16(Ah0, B[0], acc0, 0, 0, 0);
      acc1 = __builtin_amdgcn_mfma_f32_16x16x32_bf16(Ah0, B[1], acc1, 0, 0, 0);
      acc0 = __builtin_amdgcn_mfma_f32_16x16x32_bf16(Al0, B[0], acc0, 0, 0, 0);
      acc1 = __builtin_amdgcn_mfma_f32_16x16x32_bf16(Al0, B[1], acc1, 0, 0, 0);
      acc0 = __builtin_amdgcn_mfma_f32_16x16x32_bf16(Ah0, B[4], acc0, 0, 0, 0);
      acc1 = __builtin_amdgcn_mfma_f32_16x16x32_bf16(Ah0, B[5], acc1, 0, 0, 0);
      acc0 = __builtin_amdgcn_mfma_f32_16x16x32_bf16(Ah1, B[2], acc0, 0, 0, 0);
      acc1 = __builtin_amdgcn_mfma_f32_16x16x32_bf16(Ah1, B[3], acc1, 0, 0, 0);
      acc0 = __builtin_amdgcn_mfma_f32_16x16x32_bf16(Al1, B[2], acc0, 0, 0, 0);
      acc1 = __builtin_amdgcn_mfma_f32_16x16x32_bf16(Al1, B[3], acc1, 0, 0, 0);
      acc0 = __builtin_amdgcn_mfma_f32_16x16x32_bf16(Ah1, B[6], acc0, 0, 0, 0);
      acc1 = __builtin_amdgcn_mfma_f32_16x16x32_bf16(Ah1, B[7], acc1, 0, 0, 0);
#pragma unroll
      for (int reg = 0; reg < 4; ++reg) {
        float s = fmaxf(acc0[reg], 0.f) * w30 + fmaxf(acc1[reg], 0.f) * w31;
        s += __shfl_xor(s, 1);
        s += __shfl_xor(s, 2);
        s += __shfl_xor(s, 4);
        s += __shfl_xor(s, 8);
        if (n16 == 0)
          scores_s[task][wave * 128 + mt * 16 + g * 4 + reg] = s;
      }
    }
  }
  __syncthreads();

  // softmax over 512 robots for each of the 2 tasks
  const int lw = tid & 63, wid = tid >> 6;
  for (int task = 0; task < 2; ++task) {
    float s0 = scores_s[task][tid], s1 = scores_s[task][tid + 256];
    float mw = wred_max(fmaxf(s0, s1));
    if (lw == 0) red_a[wid] = mw;
    __syncthreads();
    float m = fmaxf(fmaxf(red_a[0], red_a[1]), fmaxf(red_a[2], red_a[3]));
    float e0 = expf(s0 - m), e1 = expf(s1 - m);
    float sw = wred_sum(e0 + e1);
    if (lw == 0) red_b[wid] = sw;
    __syncthreads();
    float inv = 1.f / (red_b[0] + red_b[1] + red_b[2] + red_b[3]);
    float* op = out + (size_t)(b * NT + t2 * 2 + task) * NR;
    op[tid]       = e0 * inv;
    op[256 + tid] = e1 * inv;
  }
}

// ---------------- launch ----------------
extern "C" void kernel_launch(void* const* d_in, const int* in_sizes, int n_in,
                              void* d_out, int out_size, void* d_ws, size_t ws_size,
                              hipStream_t stream)
{
  const float* rs   = (const float*)d_in[0];
  const float* ts   = (const float*)d_in[1];
  const float* r_w1 = (const float*)d_in[2];  const float* r_b1 = (const float*)d_in[3];
  const float* r_w2 = (const float*)d_in[4];  const float* r_b2 = (const float*)d_in[5];
  const float* t_w1 = (const float*)d_in[6];  const float* t_b1 = (const float*)d_in[7];
  const float* t_w2 = (const float*)d_in[8];  const float* t_b2 = (const float*)d_in[9];
  const float* wq   = (const float*)d_in[10]; const float* bq   = (const float*)d_in[11];
  const float* wk   = (const float*)d_in[12]; const float* bk   = (const float*)d_in[13];
  const float* wv   = (const float*)d_in[14]; const float* bv   = (const float*)d_in[15];
  const float* wo   = (const float*)d_in[16]; const float* bo   = (const float*)d_in[17];
  const float* a_w1 = (const float*)d_in[18]; const float* a_b1 = (const float*)d_in[19];
  const float* a_w2 = (const float*)d_in[20]; const float* a_b2 = (const float*)d_in[21];
  const float* a_w3 = (const float*)d_in[22]; const float* a_b3 = (const float*)d_in[23];

  float* wsf   = (float*)d_ws;
  float* kbuf  = wsf;                                   // 32*512*64
  float* vbuf  = kbuf  + (size_t)NB * NR * 64;          // 32*512*64
  float* rpbuf = vbuf  + (size_t)NB * NR * 64;          // 32*512*64
  float* qbuf  = rpbuf + (size_t)NB * NR * 64;          // 32*128*64
  float* tpbuf = qbuf  + (size_t)NB * NT * 64;          // 32*128*64
  unsigned short* w2f = (unsigned short*)(tpbuf + (size_t)NB * NT * 64); // 8*64*8

  enc_kernel<<<dim3(321), dim3(256), 0, stream>>>(
      rs, ts, r_w1, r_b1, r_w2, r_b2, t_w1, t_b1, t_w2, t_b2,
      wq, bq, wk, bk, wv, bv, a_w1, a_w2, kbuf, vbuf, rpbuf, qbuf, w2f);

  attn_kernel<<<dim3(1024), dim3(256), 0, stream>>>(
      qbuf, kbuf, vbuf, wo, bo, a_w1, a_b1, tpbuf);

  pair_kernel<<<dim3(2048), dim3(256), 0, stream>>>(
      tpbuf, rpbuf, w2f, a_b2, a_w3, (float*)d_out);
}

// Round 5
// 226.689 us; speedup vs baseline: 1.3316x; 1.1585x over previous
//
#include <hip/hip_runtime.h>
#include <math.h>

#define NB 32
#define NR 512
#define NT 128

typedef __attribute__((ext_vector_type(8))) short short8;
typedef __attribute__((ext_vector_type(4))) float f32x4;

// ---------------- wave (64-lane) reductions ----------------
__device__ __forceinline__ float wred_max(float v){
#pragma unroll
  for (int o = 32; o > 0; o >>= 1) v = fmaxf(v, __shfl_xor(v, o));
  return v;
}
__device__ __forceinline__ float wred_sum(float v){
#pragma unroll
  for (int o = 32; o > 0; o >>= 1) v += __shfl_xor(v, o);
  return v;
}
__device__ __forceinline__ float dot4(float4 a, float4 b){
  return a.x * b.x + a.y * b.y + a.z * b.z + a.w * b.w;
}

// ---------------- encoder kernel (+ fused W2-frag prep in block 320) -------
__global__ __launch_bounds__(256) void enc_kernel(
    const float* __restrict__ rs, const float* __restrict__ ts,
    const float* __restrict__ r_w1, const float* __restrict__ r_b1,
    const float* __restrict__ r_w2, const float* __restrict__ r_b2,
    const float* __restrict__ t_w1, const float* __restrict__ t_b1,
    const float* __restrict__ t_w2, const float* __restrict__ t_b2,
    const float* __restrict__ wq, const float* __restrict__ bq,
    const float* __restrict__ wk, const float* __restrict__ bk,
    const float* __restrict__ wv, const float* __restrict__ bv,
    const float* __restrict__ a_w1, const float* __restrict__ a_w2,
    float* __restrict__ kbuf, float* __restrict__ vbuf,
    float* __restrict__ rpbuf, float* __restrict__ qbuf,
    unsigned short* __restrict__ w2f)
{
  __shared__ float w1s[448];
  __shared__ float wss[4096];
  __shared__ float h_s[64 * 66];
  __shared__ float rf_s[64 * 66];

  const int tid = threadIdx.x;
  const int blk = blockIdx.x;

  if (blk == 320) {        // fused prep: split a_w2 into hi/lo bf16 B-frags
    if (tid < 64) {
      int l = tid, n16 = l & 15, g = l >> 4;
      for (int f = 0; f < 8; ++f) {
        int ntile = f & 1, ks = (f >> 1) & 1, part = f >> 2;
        for (int j = 0; j < 8; ++j) {
          int k = ks * 32 + g * 8 + j;
          int n = ntile * 16 + n16;
          unsigned wb = __float_as_uint(a_w2[k * 32 + n]);
          unsigned hib = wb & 0xffff0000u;
          float lof = __uint_as_float(wb) - __uint_as_float(hib);
          unsigned lob = __float_as_uint(lof) & 0xffff0000u;
          w2f[((size_t)f * 64 + l) * 8 + j] =
              (unsigned short)((part == 0 ? hib : lob) >> 16);
        }
      }
    }
    return;
  }

  const int rb = tid >> 2, t4 = tid & 3;
  const bool robot = blk < 256;

  if (robot) {
    if (tid < 112) ((float4*)w1s)[tid] = ((const float4*)r_w1)[tid];
#pragma unroll
    for (int c = 0; c < 4; ++c)
      ((float4*)wss)[c * 256 + tid] = ((const float4*)r_w2)[c * 256 + tid];
  } else {
    if (tid < 96) ((float4*)w1s)[tid] = ((const float4*)t_w1)[tid];
#pragma unroll
    for (int c = 0; c < 4; ++c)
      ((float4*)wss)[c * 256 + tid] = ((const float4*)t_w2)[c * 256 + tid];
  }

  int g, K1;
  const float* xin; const float* b1; const float* b2;
  if (robot) { g = blk * 64 + rb;        K1 = 7; xin = rs + (size_t)g * 7; b1 = r_b1; b2 = r_b2; }
  else       { g = (blk - 256) * 64 + rb; K1 = 6; xin = ts + (size_t)g * 6; b1 = t_b1; b2 = t_b2; }

  float x[7];
  for (int k = 0; k < K1; ++k) x[k] = xin[k];
  __syncthreads();

  {
    float acc[16];
#pragma unroll
    for (int jj = 0; jj < 16; ++jj) acc[jj] = b1[t4 * 16 + jj];
    for (int k = 0; k < K1; ++k) {
      float xv = x[k];
#pragma unroll
      for (int jj = 0; jj < 16; ++jj) acc[jj] += xv * w1s[k * 64 + t4 * 16 + jj];
    }
#pragma unroll
    for (int jj = 0; jj < 16; ++jj) h_s[rb * 66 + t4 * 16 + jj] = fmaxf(acc[jj], 0.f);
  }
  __syncthreads();

  {
    float acc[16];
#pragma unroll
    for (int jj = 0; jj < 16; ++jj) acc[jj] = b2[t4 * 16 + jj];
    for (int k = 0; k < 64; ++k) {
      float hv = h_s[rb * 66 + k];
      const float4* wr = (const float4*)(wss + k * 64 + t4 * 16);
#pragma unroll
      for (int j4 = 0; j4 < 4; ++j4) {
        float4 w = wr[j4];
        acc[j4 * 4 + 0] += hv * w.x; acc[j4 * 4 + 1] += hv * w.y;
        acc[j4 * 4 + 2] += hv * w.z; acc[j4 * 4 + 3] += hv * w.w;
      }
    }
#pragma unroll
    for (int jj = 0; jj < 16; ++jj) rf_s[rb * 66 + t4 * 16 + jj] = fmaxf(acc[jj], 0.f);
  }

  const float* wp[3]; const float* bp[3]; float* op[3]; int npass;
  if (robot) {
    wp[0] = wk; bp[0] = bk;      op[0] = kbuf;
    wp[1] = wv; bp[1] = bv;      op[1] = vbuf;
    wp[2] = a_w1 + 64 * 64; bp[2] = nullptr; op[2] = rpbuf;
    npass = 3;
  } else {
    wp[0] = wq; bp[0] = bq; op[0] = qbuf; npass = 1;
  }
  for (int p = 0; p < npass; ++p) {
    __syncthreads();
#pragma unroll
    for (int c = 0; c < 4; ++c)
      ((float4*)wss)[c * 256 + tid] = ((const float4*)wp[p])[c * 256 + tid];
    __syncthreads();
    float acc[16];
#pragma unroll
    for (int jj = 0; jj < 16; ++jj) acc[jj] = bp[p] ? bp[p][t4 * 16 + jj] : 0.f;
    for (int k = 0; k < 64; ++k) {
      float hv = rf_s[rb * 66 + k];
      const float4* wr = (const float4*)(wss + k * 64 + t4 * 16);
#pragma unroll
      for (int j4 = 0; j4 < 4; ++j4) {
        float4 w = wr[j4];
        acc[j4 * 4 + 0] += hv * w.x; acc[j4 * 4 + 1] += hv * w.y;
        acc[j4 * 4 + 2] += hv * w.z; acc[j4 * 4 + 3] += hv * w.w;
      }
    }
    float4* o4 = (float4*)(op[p] + (size_t)g * 64 + t4 * 16);
#pragma unroll
    for (int j4 = 0; j4 < 4; ++j4)
      o4[j4] = make_float4(acc[j4 * 4 + 0], acc[j4 * 4 + 1], acc[j4 * 4 + 2], acc[j4 * 4 + 3]);
  }
}

// ---------------- attention kernel v2: 2 tasks/block, occupancy diet -------
// 2048 blocks x 256 thr. LDS ~20 KB, VGPR capped via launch_bounds(256,4).
// Phase A: thread owns fixed head h=tid&3; q slices (2 tasks x 16f) in regs;
// K streamed 16 floats/iter (coalesced 16B/lane).
#define LGS 520   // stride: 8h+r bank pattern -> max 2-way (free)
__global__ __launch_bounds__(256, 4) void attn_kernel(
    const float* __restrict__ qbuf, const float* __restrict__ kbuf,
    const float* __restrict__ vbuf,
    const float* __restrict__ wo, const float* __restrict__ bo,
    const float* __restrict__ a_w1, const float* __restrict__ a_b1,
    float* __restrict__ tpbuf)
{
  __shared__ float qt_s[2 * 64];        // q in phase A, tf in phase D/E
  __shared__ float lg[2][4 * LGS];      // [task][head*LGS + r]
  __shared__ float inv_s[8];
  __shared__ float cp[4][2 * 64];
  __shared__ float ctx_s[2 * 64];

  const int tid = threadIdx.x;
  const int jj = blockIdx.x & 31;
  const int b  = (jj & 7) * 4 + (jj >> 3);   // XCD-locality swizzle
  const int t0 = (blockIdx.x >> 5) * 2;      // 64 task-pairs

  if (tid < 32) {
    int tt = tid >> 4, i4 = tid & 15;
    float4 v = ((const float4*)(qbuf + (size_t)(b * NT + t0 + tt) * 64))[i4];
    v.x *= 0.25f; v.y *= 0.25f; v.z *= 0.25f; v.w *= 0.25f;   // 1/sqrt(16)
    ((float4*)qt_s)[tid] = v;
  }
  __syncthreads();

  // phase A: logits. h fixed per thread, r strides by 64.
  {
    const int h = tid & 3;
    const int r0 = tid >> 2;
    const float4* q0 = (const float4*)(qt_s + h * 16);        // task 0 slice
    const float4* q1 = (const float4*)(qt_s + 64 + h * 16);   // task 1 slice
    float4 q0a = q0[0], q0b = q0[1], q0c = q0[2], q0d = q0[3];
    float4 q1a = q1[0], q1b = q1[1], q1c = q1[2], q1d = q1[3];
    const float* kb0 = kbuf + (size_t)b * NR * 64 + h * 16;
    for (int it = 0; it < 8; ++it) {
      int r = r0 + it * 64;
      const float4* k4 = (const float4*)(kb0 + (size_t)r * 64);
      float4 ka = k4[0], kb = k4[1], kc = k4[2], kd = k4[3];
      float s0 = dot4(q0a, ka) + dot4(q0b, kb) + dot4(q0c, kc) + dot4(q0d, kd);
      float s1 = dot4(q1a, ka) + dot4(q1b, kb) + dot4(q1c, kc) + dot4(q1d, kd);
      lg[0][h * LGS + r] = s0;
      lg[1][h * LGS + r] = s1;
    }
  }
  __syncthreads();

  // phase B: per-(task,head) softmax; 4 waves x 2 pairs
  {
    int w = tid >> 6, lane = tid & 63;
    for (int p = 0; p < 2; ++p) {
      int pr = w * 2 + p, tt = pr >> 2, hh = pr & 3;
      float* row = &lg[tt][hh * LGS];
      float v0[8];
#pragma unroll
      for (int u = 0; u < 8; ++u) v0[u] = row[u * 64 + lane];
      float m = v0[0];
#pragma unroll
      for (int u = 1; u < 8; ++u) m = fmaxf(m, v0[u]);
      m = wred_max(m);
      float s = 0.f;
#pragma unroll
      for (int u = 0; u < 8; ++u) {
        float e = expf(v0[u] - m);
        row[u * 64 + lane] = e;
        s += e;
      }
      s = wred_sum(s);
      if (lane == 0) inv_s[tt * 4 + hh] = 1.f / s;
    }
  }
  __syncthreads();

  // phase C: ctx = p.v  (r chunked over 4 waves)
  {
    int od = tid & 63, ch = tid >> 6;
    int h = od >> 4, d = od & 15;
    float acc0 = 0.f, acc1 = 0.f;
    const float* vptr = vbuf + (size_t)b * NR * 64 + h * 16 + d;
#pragma unroll 4
    for (int u = 0; u < 128; ++u) {
      int r = ch * 128 + u;
      float vv = vptr[(size_t)r * 64];
      acc0 += lg[0][h * LGS + r] * vv;
      acc1 += lg[1][h * LGS + r] * vv;
    }
    cp[ch][od]      = acc0;
    cp[ch][64 + od] = acc1;
  }
  __syncthreads();
  if (tid < 128) {
    int od = tid & 63, h = od >> 4;
    ctx_s[tid] = (cp[0][tid] + cp[1][tid] + cp[2][tid] + cp[3][tid]) *
                 inv_s[(tid >> 6) * 4 + h];
  }
  __syncthreads();

  // phase D: tf = ctx @ wo + bo  -> qt_s
  {
    int jd = tid & 63, kc = tid >> 6;
    float p0 = 0.f, p1 = 0.f;
    for (int k = 0; k < 16; ++k) {
      float w = wo[(kc * 16 + k) * 64 + jd];
      p0 += ctx_s[kc * 16 + k] * w;
      p1 += ctx_s[64 + kc * 16 + k] * w;
    }
    cp[kc][jd]      = p0;
    cp[kc][64 + jd] = p1;
  }
  __syncthreads();
  if (tid < 128) {
    int jd = tid & 63;
    qt_s[tid] = cp[0][tid] + cp[1][tid] + cp[2][tid] + cp[3][tid] + bo[jd];
  }
  __syncthreads();

  // phase E: tp = tf @ a_w1[:64] + a_b1 -> tpbuf
  {
    int jd = tid & 63, kc = tid >> 6;
    float p0 = 0.f, p1 = 0.f;
    for (int k = 0; k < 16; ++k) {
      float w = a_w1[(kc * 16 + k) * 64 + jd];
      p0 += qt_s[kc * 16 + k] * w;
      p1 += qt_s[64 + kc * 16 + k] * w;
    }
    cp[kc][jd]      = p0;
    cp[kc][64 + jd] = p1;
  }
  __syncthreads();
  if (tid < 128) {
    int jd = tid & 63;
    tpbuf[(size_t)(b * NT + t0) * 64 + tid] =
        cp[0][tid] + cp[1][tid] + cp[2][tid] + cp[3][tid] + a_b1[jd];
  }
}

// ---------------- pairwise allocation kernel (v4, unchanged) ---------------
__device__ __forceinline__ void mk_frags(float4 ra, float4 rb,
                                         float4 ta, float4 tb,
                                         short8* Ah, short8* Al)
{
  float x0 = fmaxf(ra.x + ta.x, 0.f), x1 = fmaxf(ra.y + ta.y, 0.f);
  float x2 = fmaxf(ra.z + ta.z, 0.f), x3 = fmaxf(ra.w + ta.w, 0.f);
  float x4 = fmaxf(rb.x + tb.x, 0.f), x5 = fmaxf(rb.y + tb.y, 0.f);
  float x6 = fmaxf(rb.z + tb.z, 0.f), x7 = fmaxf(rb.w + tb.w, 0.f);
  unsigned u0 = __float_as_uint(x0), u1 = __float_as_uint(x1);
  unsigned u2 = __float_as_uint(x2), u3 = __float_as_uint(x3);
  unsigned u4 = __float_as_uint(x4), u5 = __float_as_uint(x5);
  unsigned u6 = __float_as_uint(x6), u7 = __float_as_uint(x7);
  unsigned m0 = __float_as_uint(x0 - __uint_as_float(u0 & 0xffff0000u));
  unsigned m1 = __float_as_uint(x1 - __uint_as_float(u1 & 0xffff0000u));
  unsigned m2 = __float_as_uint(x2 - __uint_as_float(u2 & 0xffff0000u));
  unsigned m3 = __float_as_uint(x3 - __uint_as_float(u3 & 0xffff0000u));
  unsigned m4 = __float_as_uint(x4 - __uint_as_float(u4 & 0xffff0000u));
  unsigned m5 = __float_as_uint(x5 - __uint_as_float(u5 & 0xffff0000u));
  unsigned m6 = __float_as_uint(x6 - __uint_as_float(u6 & 0xffff0000u));
  unsigned m7 = __float_as_uint(x7 - __uint_as_float(u7 & 0xffff0000u));
  int4 hi = make_int4((int)((u1 & 0xffff0000u) | (u0 >> 16)),
                      (int)((u3 & 0xffff0000u) | (u2 >> 16)),
                      (int)((u5 & 0xffff0000u) | (u4 >> 16)),
                      (int)((u7 & 0xffff0000u) | (u6 >> 16)));
  int4 lo = make_int4((int)((m1 & 0xffff0000u) | (m0 >> 16)),
                      (int)((m3 & 0xffff0000u) | (m2 >> 16)),
                      (int)((m5 & 0xffff0000u) | (m4 >> 16)),
                      (int)((m7 & 0xffff0000u) | (m6 >> 16)));
  *Ah = __builtin_bit_cast(short8, hi);
  *Al = __builtin_bit_cast(short8, lo);
}

__global__ __launch_bounds__(256) void pair_kernel(
    const float* __restrict__ tpbuf, const float* __restrict__ rpbuf,
    const unsigned short* __restrict__ w2f,
    const float* __restrict__ a_b2, const float* __restrict__ a_w3,
    float* __restrict__ out)
{
  __shared__ float scores_s[2][512];
  __shared__ float red_a[4];
  __shared__ float red_b[4];

  const int tid = threadIdx.x;
  const int jj = blockIdx.x & 31;
  const int b  = (jj & 7) * 4 + (jj >> 3);   // XCD-locality swizzle
  const int t2 = blockIdx.x >> 5;            // task pair [0,64)
  const int wave = tid >> 6, lane = tid & 63;
  const int n16 = lane & 15, g = lane >> 4;

  short8 B[8];
#pragma unroll
  for (int f = 0; f < 8; ++f)
    B[f] = __builtin_bit_cast(short8, ((const int4*)w2f)[f * 64 + lane]);

  const float* tpA = tpbuf + (size_t)(b * NT + t2 * 2) * 64 + g * 8;
  const float* tpB = tpA + 64;
  float4 tA0a = *(const float4*)(tpA),      tA0b = *(const float4*)(tpA + 4);
  float4 tA1a = *(const float4*)(tpA + 32), tA1b = *(const float4*)(tpA + 36);
  float4 tB0a = *(const float4*)(tpB),      tB0b = *(const float4*)(tpB + 4);
  float4 tB1a = *(const float4*)(tpB + 32), tB1b = *(const float4*)(tpB + 36);

  float b20 = a_b2[n16], b21 = a_b2[16 + n16];
  float w30 = a_w3[n16], w31 = a_w3[16 + n16];

  const float* rpb = rpbuf + (size_t)b * NR * 64 + g * 8;

#pragma unroll
  for (int mt = 0; mt < 8; ++mt) {
    const float* rp = rpb + (size_t)(wave * 128 + mt * 16 + n16) * 64;
    float4 ra0 = *(const float4*)(rp);
    float4 rb0 = *(const float4*)(rp + 4);
    float4 ra1 = *(const float4*)(rp + 32);
    float4 rb1 = *(const float4*)(rp + 36);

#pragma unroll
    for (int task = 0; task < 2; ++task) {
      short8 Ah0, Al0, Ah1, Al1;
      if (task == 0) {
        mk_frags(ra0, rb0, tA0a, tA0b, &Ah0, &Al0);
        mk_frags(ra1, rb1, tA1a, tA1b, &Ah1, &Al1);
      } else {
        mk_frags(ra0, rb0, tB0a, tB0b, &Ah0, &Al0);
        mk_frags(ra1, rb1, tB1a, tB1b, &Ah1, &Al1);
      }
      f32x4 acc0 = (f32x4){b20, b20, b20, b20};
      f32x4 acc1 = (f32x4){b21, b21, b21, b21};
      acc0 = __builtin_amdgcn_mfma_f32_16x16x32_bf16(Ah0, B[0], acc0, 0, 0, 0);
      acc1 = __builtin_amdgcn_mfma_f32_16x16x32_bf16(Ah0, B[1], acc1, 0, 0, 0);
      acc0 = __builtin_amdgcn_mfma_f32_16x16x32_bf16(Al0, B[0], acc0, 0, 0, 0);
      acc1 = __builtin_amdgcn_mfma_f32_16x16x32_bf16(Al0, B[1], acc1, 0, 0, 0);
      acc0 = __builtin_amdgcn_mfma_f32_16x16x32_bf16(Ah0, B[4], acc0, 0, 0, 0);
      acc1 = __builtin_amdgcn_mfma_f32_16x16x32_bf16(Ah0, B[5], acc1, 0, 0, 0);
      acc0 = __builtin_amdgcn_mfma_f32_16x16x32_bf16(Ah1, B[2], acc0, 0, 0, 0);
      acc1 = __builtin_amdgcn_mfma_f32_16x16x32_bf16(Ah1, B[3], acc1, 0, 0, 0);
      acc0 = __builtin_amdgcn_mfma_f32_16x16x32_bf16(Al1, B[2], acc0, 0, 0, 0);
      acc1 = __builtin_amdgcn_mfma_f32_16x16x32_bf16(Al1, B[3], acc1, 0, 0, 0);
      acc0 = __builtin_amdgcn_mfma_f32_16x16x32_bf16(Ah1, B[6], acc0, 0, 0, 0);
      acc1 = __builtin_amdgcn_mfma_f32_16x16x32_bf16(Ah1, B[7], acc1, 0, 0, 0);
#pragma unroll
      for (int reg = 0; reg < 4; ++reg) {
        float s = fmaxf(acc0[reg], 0.f) * w30 + fmaxf(acc1[reg], 0.f) * w31;
        s += __shfl_xor(s, 1);
        s += __shfl_xor(s, 2);
        s += __shfl_xor(s, 4);
        s += __shfl_xor(s, 8);
        if (n16 == 0)
          scores_s[task][wave * 128 + mt * 16 + g * 4 + reg] = s;
      }
    }
  }
  __syncthreads();

  const int lw = tid & 63, wid = tid >> 6;
  for (int task = 0; task < 2; ++task) {
    float s0 = scores_s[task][tid], s1 = scores_s[task][tid + 256];
    float mw = wred_max(fmaxf(s0, s1));
    if (lw == 0) red_a[wid] = mw;
    __syncthreads();
    float m = fmaxf(fmaxf(red_a[0], red_a[1]), fmaxf(red_a[2], red_a[3]));
    float e0 = expf(s0 - m), e1 = expf(s1 - m);
    float sw = wred_sum(e0 + e1);
    if (lw == 0) red_b[wid] = sw;
    __syncthreads();
    float inv = 1.f / (red_b[0] + red_b[1] + red_b[2] + red_b[3]);
    float* op = out + (size_t)(b * NT + t2 * 2 + task) * NR;
    op[tid]       = e0 * inv;
    op[256 + tid] = e1 * inv;
  }
}

// ---------------- launch ----------------
extern "C" void kernel_launch(void* const* d_in, const int* in_sizes, int n_in,
                              void* d_out, int out_size, void* d_ws, size_t ws_size,
                              hipStream_t stream)
{
  const float* rs   = (const float*)d_in[0];
  const float* ts   = (const float*)d_in[1];
  const float* r_w1 = (const float*)d_in[2];  const float* r_b1 = (const float*)d_in[3];
  const float* r_w2 = (const float*)d_in[4];  const float* r_b2 = (const float*)d_in[5];
  const float* t_w1 = (const float*)d_in[6];  const float* t_b1 = (const float*)d_in[7];
  const float* t_w2 = (const float*)d_in[8];  const float* t_b2 = (const float*)d_in[9];
  const float* wq   = (const float*)d_in[10]; const float* bq   = (const float*)d_in[11];
  const float* wk   = (const float*)d_in[12]; const float* bk   = (const float*)d_in[13];
  const float* wv   = (const float*)d_in[14]; const float* bv   = (const float*)d_in[15];
  const float* wo   = (const float*)d_in[16]; const float* bo   = (const float*)d_in[17];
  const float* a_w1 = (const float*)d_in[18]; const float* a_b1 = (const float*)d_in[19];
  const float* a_w2 = (const float*)d_in[20]; const float* a_b2 = (const float*)d_in[21];
  const float* a_w3 = (const float*)d_in[22]; const float* a_b3 = (const float*)d_in[23];

  float* wsf   = (float*)d_ws;
  float* kbuf  = wsf;                                   // 32*512*64
  float* vbuf  = kbuf  + (size_t)NB * NR * 64;          // 32*512*64
  float* rpbuf = vbuf  + (size_t)NB * NR * 64;          // 32*512*64
  float* qbuf  = rpbuf + (size_t)NB * NR * 64;          // 32*128*64
  float* tpbuf = qbuf  + (size_t)NB * NT * 64;          // 32*128*64
  unsigned short* w2f = (unsigned short*)(tpbuf + (size_t)NB * NT * 64); // 8*64*8

  enc_kernel<<<dim3(321), dim3(256), 0, stream>>>(
      rs, ts, r_w1, r_b1, r_w2, r_b2, t_w1, t_b1, t_w2, t_b2,
      wq, bq, wk, bk, wv, bv, a_w1, a_w2, kbuf, vbuf, rpbuf, qbuf, w2f);

  attn_kernel<<<dim3(2048), dim3(256), 0, stream>>>(
      qbuf, kbuf, vbuf, wo, bo, a_w1, a_b1, tpbuf);

  pair_kernel<<<dim3(2048), dim3(256), 0, stream>>>(
      tpbuf, rpbuf, w2f, a_b2, a_w3, (float*)d_out);
}

// Round 7
// 222.089 us; speedup vs baseline: 1.3592x; 1.0207x over previous
//
#include <hip/hip_runtime.h>
#include <math.h>

#define NB 32
#define NR 512
#define NT 128

typedef __attribute__((ext_vector_type(8))) short short8;
typedef __attribute__((ext_vector_type(4))) float f32x4;
typedef __attribute__((ext_vector_type(2))) float f32x2;

// ---------------- wave (64-lane) reductions ----------------
__device__ __forceinline__ float wred_max(float v){
#pragma unroll
  for (int o = 32; o > 0; o >>= 1) v = fmaxf(v, __shfl_xor(v, o));
  return v;
}
__device__ __forceinline__ float wred_sum(float v){
#pragma unroll
  for (int o = 32; o > 0; o >>= 1) v += __shfl_xor(v, o);
  return v;
}
__device__ __forceinline__ float dot4(float4 a, float4 b){
  return a.x * b.x + a.y * b.y + a.z * b.z + a.w * b.w;
}

// ---------------- encoder kernel v2: 32 rows/block (641 blocks) ------------
// blocks 0..511: robots; 512..639: tasks; 640: W2-frag prep.
__global__ __launch_bounds__(256) void enc_kernel(
    const float* __restrict__ rs, const float* __restrict__ ts,
    const float* __restrict__ r_w1, const float* __restrict__ r_b1,
    const float* __restrict__ r_w2, const float* __restrict__ r_b2,
    const float* __restrict__ t_w1, const float* __restrict__ t_b1,
    const float* __restrict__ t_w2, const float* __restrict__ t_b2,
    const float* __restrict__ wq, const float* __restrict__ bq,
    const float* __restrict__ wk, const float* __restrict__ bk,
    const float* __restrict__ wv, const float* __restrict__ bv,
    const float* __restrict__ a_w1, const float* __restrict__ a_w2,
    float* __restrict__ kbuf, float* __restrict__ vbuf,
    float* __restrict__ rpbuf, float* __restrict__ qbuf,
    unsigned short* __restrict__ w2f)
{
  __shared__ float w1s[448];
  __shared__ float wss[4096];
  __shared__ float h_s[32 * 66];
  __shared__ float rf_s[32 * 66];

  const int tid = threadIdx.x;
  const int blk = blockIdx.x;

  if (blk == 640) {        // fused prep: split a_w2 into hi/lo bf16 B-frags
    if (tid < 64) {
      int l = tid, n16 = l & 15, g = l >> 4;
      for (int f = 0; f < 8; ++f) {
        int ntile = f & 1, ks = (f >> 1) & 1, part = f >> 2;
        for (int j = 0; j < 8; ++j) {
          int k = ks * 32 + g * 8 + j;
          int n = ntile * 16 + n16;
          unsigned wb = __float_as_uint(a_w2[k * 32 + n]);
          unsigned hib = wb & 0xffff0000u;
          float lof = __uint_as_float(wb) - __uint_as_float(hib);
          unsigned lob = __float_as_uint(lof) & 0xffff0000u;
          w2f[((size_t)f * 64 + l) * 8 + j] =
              (unsigned short)((part == 0 ? hib : lob) >> 16);
        }
      }
    }
    return;
  }

  const int rb = tid >> 3, t8 = tid & 7;
  const bool robot = blk < 512;

  if (robot) {
    if (tid < 112) ((float4*)w1s)[tid] = ((const float4*)r_w1)[tid];
#pragma unroll
    for (int c = 0; c < 4; ++c)
      ((float4*)wss)[c * 256 + tid] = ((const float4*)r_w2)[c * 256 + tid];
  } else {
    if (tid < 96) ((float4*)w1s)[tid] = ((const float4*)t_w1)[tid];
#pragma unroll
    for (int c = 0; c < 4; ++c)
      ((float4*)wss)[c * 256 + tid] = ((const float4*)t_w2)[c * 256 + tid];
  }

  int g, K1;
  const float* xin; const float* b1; const float* b2;
  if (robot) { g = blk * 32 + rb;          K1 = 7; xin = rs + (size_t)g * 7; b1 = r_b1; b2 = r_b2; }
  else       { g = (blk - 512) * 32 + rb;  K1 = 6; xin = ts + (size_t)g * 6; b1 = t_b1; b2 = t_b2; }

  float x[7];
  for (int k = 0; k < K1; ++k) x[k] = xin[k];
  __syncthreads();

  // stage 1: hidden = relu(x @ W1 + b1)
  {
    float acc[8];
#pragma unroll
    for (int jj = 0; jj < 8; ++jj) acc[jj] = b1[t8 * 8 + jj];
    for (int k = 0; k < K1; ++k) {
      float xv = x[k];
#pragma unroll
      for (int jj = 0; jj < 8; ++jj) acc[jj] += xv * w1s[k * 64 + t8 * 8 + jj];
    }
#pragma unroll
    for (int jj = 0; jj < 8; ++jj) h_s[rb * 66 + t8 * 8 + jj] = fmaxf(acc[jj], 0.f);
  }
  __syncthreads();

  // stage 2: rf = relu(hidden @ W2 + b2)
  {
    float acc[8];
#pragma unroll
    for (int jj = 0; jj < 8; ++jj) acc[jj] = b2[t8 * 8 + jj];
    for (int k = 0; k < 64; ++k) {
      float hv = h_s[rb * 66 + k];
      const float4* wr = (const float4*)(wss + k * 64 + t8 * 8);
#pragma unroll
      for (int j4 = 0; j4 < 2; ++j4) {
        float4 w = wr[j4];
        acc[j4 * 4 + 0] += hv * w.x; acc[j4 * 4 + 1] += hv * w.y;
        acc[j4 * 4 + 2] += hv * w.z; acc[j4 * 4 + 3] += hv * w.w;
      }
    }
#pragma unroll
    for (int jj = 0; jj < 8; ++jj) rf_s[rb * 66 + t8 * 8 + jj] = fmaxf(acc[jj], 0.f);
  }

  // stage 3: projection passes
  const float* wp[3]; const float* bp[3]; float* op[3]; int npass;
  if (robot) {
    wp[0] = wk; bp[0] = bk;      op[0] = kbuf;
    wp[1] = wv; bp[1] = bv;      op[1] = vbuf;
    wp[2] = a_w1 + 64 * 64; bp[2] = nullptr; op[2] = rpbuf;
    npass = 3;
  } else {
    wp[0] = wq; bp[0] = bq; op[0] = qbuf; npass = 1;
  }
  for (int p = 0; p < npass; ++p) {
    __syncthreads();
#pragma unroll
    for (int c = 0; c < 4; ++c)
      ((float4*)wss)[c * 256 + tid] = ((const float4*)wp[p])[c * 256 + tid];
    __syncthreads();
    float acc[8];
#pragma unroll
    for (int jj = 0; jj < 8; ++jj) acc[jj] = bp[p] ? bp[p][t8 * 8 + jj] : 0.f;
    for (int k = 0; k < 64; ++k) {
      float hv = rf_s[rb * 66 + k];
      const float4* wr = (const float4*)(wss + k * 64 + t8 * 8);
#pragma unroll
      for (int j4 = 0; j4 < 2; ++j4) {
        float4 w = wr[j4];
        acc[j4 * 4 + 0] += hv * w.x; acc[j4 * 4 + 1] += hv * w.y;
        acc[j4 * 4 + 2] += hv * w.z; acc[j4 * 4 + 3] += hv * w.w;
      }
    }
    float4* o4 = (float4*)(op[p] + (size_t)g * 64 + t8 * 8);
    o4[0] = make_float4(acc[0], acc[1], acc[2], acc[3]);
    o4[1] = make_float4(acc[4], acc[5], acc[6], acc[7]);
  }
}

// ---------------- attention kernel v2 (unchanged from round 5) -------------
#define LGS 520
__global__ __launch_bounds__(256, 4) void attn_kernel(
    const float* __restrict__ qbuf, const float* __restrict__ kbuf,
    const float* __restrict__ vbuf,
    const float* __restrict__ wo, const float* __restrict__ bo,
    const float* __restrict__ a_w1, const float* __restrict__ a_b1,
    float* __restrict__ tpbuf)
{
  __shared__ float qt_s[2 * 64];
  __shared__ float lg[2][4 * LGS];
  __shared__ float inv_s[8];
  __shared__ float cp[4][2 * 64];
  __shared__ float ctx_s[2 * 64];

  const int tid = threadIdx.x;
  const int jj = blockIdx.x & 31;
  const int b  = (jj & 7) * 4 + (jj >> 3);
  const int t0 = (blockIdx.x >> 5) * 2;

  if (tid < 32) {
    int tt = tid >> 4, i4 = tid & 15;
    float4 v = ((const float4*)(qbuf + (size_t)(b * NT + t0 + tt) * 64))[i4];
    v.x *= 0.25f; v.y *= 0.25f; v.z *= 0.25f; v.w *= 0.25f;
    ((float4*)qt_s)[tid] = v;
  }
  __syncthreads();

  {
    const int h = tid & 3;
    const int r0 = tid >> 2;
    const float4* q0 = (const float4*)(qt_s + h * 16);
    const float4* q1 = (const float4*)(qt_s + 64 + h * 16);
    float4 q0a = q0[0], q0b = q0[1], q0c = q0[2], q0d = q0[3];
    float4 q1a = q1[0], q1b = q1[1], q1c = q1[2], q1d = q1[3];
    const float* kb0 = kbuf + (size_t)b * NR * 64 + h * 16;
    for (int it = 0; it < 8; ++it) {
      int r = r0 + it * 64;
      const float4* k4 = (const float4*)(kb0 + (size_t)r * 64);
      float4 ka = k4[0], kb = k4[1], kc = k4[2], kd = k4[3];
      float s0 = dot4(q0a, ka) + dot4(q0b, kb) + dot4(q0c, kc) + dot4(q0d, kd);
      float s1 = dot4(q1a, ka) + dot4(q1b, kb) + dot4(q1c, kc) + dot4(q1d, kd);
      lg[0][h * LGS + r] = s0;
      lg[1][h * LGS + r] = s1;
    }
  }
  __syncthreads();

  {
    int w = tid >> 6, lane = tid & 63;
    for (int p = 0; p < 2; ++p) {
      int pr = w * 2 + p, tt = pr >> 2, hh = pr & 3;
      float* row = &lg[tt][hh * LGS];
      float v0[8];
#pragma unroll
      for (int u = 0; u < 8; ++u) v0[u] = row[u * 64 + lane];
      float m = v0[0];
#pragma unroll
      for (int u = 1; u < 8; ++u) m = fmaxf(m, v0[u]);
      m = wred_max(m);
      float s = 0.f;
#pragma unroll
      for (int u = 0; u < 8; ++u) {
        float e = expf(v0[u] - m);
        row[u * 64 + lane] = e;
        s += e;
      }
      s = wred_sum(s);
      if (lane == 0) inv_s[tt * 4 + hh] = 1.f / s;
    }
  }
  __syncthreads();

  {
    int od = tid & 63, ch = tid >> 6;
    int h = od >> 4, d = od & 15;
    float acc0 = 0.f, acc1 = 0.f;
    const float* vptr = vbuf + (size_t)b * NR * 64 + h * 16 + d;
#pragma unroll 4
    for (int u = 0; u < 128; ++u) {
      int r = ch * 128 + u;
      float vv = vptr[(size_t)r * 64];
      acc0 += lg[0][h * LGS + r] * vv;
      acc1 += lg[1][h * LGS + r] * vv;
    }
    cp[ch][od]      = acc0;
    cp[ch][64 + od] = acc1;
  }
  __syncthreads();
  if (tid < 128) {
    int od = tid & 63, h = od >> 4;
    ctx_s[tid] = (cp[0][tid] + cp[1][tid] + cp[2][tid] + cp[3][tid]) *
                 inv_s[(tid >> 6) * 4 + h];
  }
  __syncthreads();

  {
    int jd = tid & 63, kc = tid >> 6;
    float p0 = 0.f, p1 = 0.f;
    for (int k = 0; k < 16; ++k) {
      float w = wo[(kc * 16 + k) * 64 + jd];
      p0 += ctx_s[kc * 16 + k] * w;
      p1 += ctx_s[64 + kc * 16 + k] * w;
    }
    cp[kc][jd]      = p0;
    cp[kc][64 + jd] = p1;
  }
  __syncthreads();
  if (tid < 128) {
    int jd = tid & 63;
    qt_s[tid] = cp[0][tid] + cp[1][tid] + cp[2][tid] + cp[3][tid] + bo[jd];
  }
  __syncthreads();

  {
    int jd = tid & 63, kc = tid >> 6;
    float p0 = 0.f, p1 = 0.f;
    for (int k = 0; k < 16; ++k) {
      float w = a_w1[(kc * 16 + k) * 64 + jd];
      p0 += qt_s[kc * 16 + k] * w;
      p1 += qt_s[64 + kc * 16 + k] * w;
    }
    cp[kc][jd]      = p0;
    cp[kc][64 + jd] = p1;
  }
  __syncthreads();
  if (tid < 128) {
    int jd = tid & 63;
    tpbuf[(size_t)(b * NT + t0) * 64 + tid] =
        cp[0][tid] + cp[1][tid] + cp[2][tid] + cp[3][tid] + a_b1[jd];
  }
}

// ---------------- pairwise allocation kernel (v5b) -------------------------
// v4 + 1-deep software prefetch; truncation hi/lo split (known-good R3-R5
// numerics) with packed f32 add/max (v_pk_add_f32 / v_pk_max_f32).
__device__ __forceinline__ void mk2(f32x2 r, f32x2 t,
                                    unsigned* h, unsigned* l)
{
  f32x2 x = r + t;                                    // v_pk_add_f32
  x = __builtin_elementwise_max(x, (f32x2){0.f, 0.f}); // v_pk_max_f32
  unsigned u0 = __float_as_uint(x.x), u1 = __float_as_uint(x.y);
  unsigned h0 = u0 & 0xffff0000u, h1 = u1 & 0xffff0000u;
  f32x2 e = x - (f32x2){__uint_as_float(h0), __uint_as_float(h1)};
  *h = (u0 >> 16) | h1;
  *l = (__float_as_uint(e.x) >> 16) | (__float_as_uint(e.y) & 0xffff0000u);
}

__device__ __forceinline__ void mk_frags(float4 ra, float4 rb,
                                         float4 ta, float4 tb,
                                         short8* Ah, short8* Al)
{
  unsigned h0, h1, h2, h3, l0, l1, l2, l3;
  mk2((f32x2){ra.x, ra.y}, (f32x2){ta.x, ta.y}, &h0, &l0);
  mk2((f32x2){ra.z, ra.w}, (f32x2){ta.z, ta.w}, &h1, &l1);
  mk2((f32x2){rb.x, rb.y}, (f32x2){tb.x, tb.y}, &h2, &l2);
  mk2((f32x2){rb.z, rb.w}, (f32x2){tb.z, tb.w}, &h3, &l3);
  *Ah = __builtin_bit_cast(short8, make_int4((int)h0, (int)h1, (int)h2, (int)h3));
  *Al = __builtin_bit_cast(short8, make_int4((int)l0, (int)l1, (int)l2, (int)l3));
}

__global__ __launch_bounds__(256) void pair_kernel(
    const float* __restrict__ tpbuf, const float* __restrict__ rpbuf,
    const unsigned short* __restrict__ w2f,
    const float* __restrict__ a_b2, const float* __restrict__ a_w3,
    float* __restrict__ out)
{
  __shared__ float scores_s[2][512];
  __shared__ float red_a[4];
  __shared__ float red_b[4];

  const int tid = threadIdx.x;
  const int jj = blockIdx.x & 31;
  const int b  = (jj & 7) * 4 + (jj >> 3);   // XCD-locality swizzle
  const int t2 = blockIdx.x >> 5;            // task pair [0,64)
  const int wave = tid >> 6, lane = tid & 63;
  const int n16 = lane & 15, g = lane >> 4;

  short8 B[8];
#pragma unroll
  for (int f = 0; f < 8; ++f)
    B[f] = __builtin_bit_cast(short8, ((const int4*)w2f)[f * 64 + lane]);

  const float* tpA = tpbuf + (size_t)(b * NT + t2 * 2) * 64 + g * 8;
  const float* tpB = tpA + 64;
  float4 tA0a = *(const float4*)(tpA),      tA0b = *(const float4*)(tpA + 4);
  float4 tA1a = *(const float4*)(tpA + 32), tA1b = *(const float4*)(tpA + 36);
  float4 tB0a = *(const float4*)(tpB),      tB0b = *(const float4*)(tpB + 4);
  float4 tB1a = *(const float4*)(tpB + 32), tB1b = *(const float4*)(tpB + 36);

  float b20 = a_b2[n16], b21 = a_b2[16 + n16];
  float w30 = a_w3[n16], w31 = a_w3[16 + n16];

  const float* rpb = rpbuf + (size_t)b * NR * 64 + g * 8;

  // prefetch mt = 0
  const float4* rp0 = (const float4*)(rpb + (size_t)(wave * 128 + n16) * 64);
  float4 ra0 = rp0[0], rb0 = rp0[1], ra1 = rp0[8], rb1 = rp0[9];

#pragma unroll
  for (int mt = 0; mt < 8; ++mt) {
    float4 na0, nb0, na1, nb1;
    if (mt < 7) {   // prefetch next mt while this one computes
      const float4* rpn =
          (const float4*)(rpb + (size_t)(wave * 128 + (mt + 1) * 16 + n16) * 64);
      na0 = rpn[0]; nb0 = rpn[1]; na1 = rpn[8]; nb1 = rpn[9];
    }

#pragma unroll
    for (int task = 0; task < 2; ++task) {
      short8 Ah0, Al0, Ah1, Al1;
      if (task == 0) {
        mk_frags(ra0, rb0, tA0a, tA0b, &Ah0, &Al0);
        mk_frags(ra1, rb1, tA1a, tA1b, &Ah1, &Al1);
      } else {
        mk_frags(ra0, rb0, tB0a, tB0b, &Ah0, &Al0);
        mk_frags(ra1, rb1, tB1a, tB1b, &Ah1, &Al1);
      }
      f32x4 acc0 = (f32x4){b20, b20, b20, b20};
      f32x4 acc1 = (f32x4){b21, b21, b21, b21};
      acc0 = __builtin_amdgcn_mfma_f32_16x16x32_bf16(Ah0, B[0], acc0, 0, 0, 0);
      acc1 = __builtin_amdgcn_mfma_f32_16x16x32_bf16(Ah0, B[1], acc1, 0, 0, 0);
      acc0 = __builtin_amdgcn_mfma_f32_16x16x32_bf16(Al0, B[0], acc0, 0, 0, 0);
      acc1 = __builtin_amdgcn_mfma_f32_16x16x32_bf16(Al0, B[1], acc1, 0, 0, 0);
      acc0 = __builtin_amdgcn_mfma_f32_16x16x32_bf16(Ah0, B[4], acc0, 0, 0, 0);
      acc1 = __builtin_amdgcn_mfma_f32_16x16x32_bf16(Ah0, B[5], acc1, 0, 0, 0);
      acc0 = __builtin_amdgcn_mfma_f32_16x16x32_bf16(Ah1, B[2], acc0, 0, 0, 0);
      acc1 = __builtin_amdgcn_mfma_f32_16x16x32_bf16(Ah1, B[3], acc1, 0, 0, 0);
      acc0 = __builtin_amdgcn_mfma_f32_16x16x32_bf16(Al1, B[2], acc0, 0, 0, 0);
      acc1 = __builtin_amdgcn_mfma_f32_16x16x32_bf16(Al1, B[3], acc1, 0, 0, 0);
      acc0 = __builtin_amdgcn_mfma_f32_16x16x32_bf16(Ah1, B[6], acc0, 0, 0, 0);
      acc1 = __builtin_amdgcn_mfma_f32_16x16x32_bf16(Ah1, B[7], acc1, 0, 0, 0);
#pragma unroll
      for (int reg = 0; reg < 4; ++reg) {
        float s = fmaxf(acc0[reg], 0.f) * w30 + fmaxf(acc1[reg], 0.f) * w31;
        s += __shfl_xor(s, 1);
        s += __shfl_xor(s, 2);
        s += __shfl_xor(s, 4);
        s += __shfl_xor(s, 8);
        if (n16 == 0)
          scores_s[task][wave * 128 + mt * 16 + g * 4 + reg] = s;
      }
    }
    ra0 = na0; rb0 = nb0; ra1 = na1; rb1 = nb1;
  }
  __syncthreads();

  const int lw = tid & 63, wid = tid >> 6;
  for (int task = 0; task < 2; ++task) {
    float s0 = scores_s[task][tid], s1 = scores_s[task][tid + 256];
    float mw = wred_max(fmaxf(s0, s1));
    if (lw == 0) red_a[wid] = mw;
    __syncthreads();
    float m = fmaxf(fmaxf(red_a[0], red_a[1]), fmaxf(red_a[2], red_a[3]));
    float e0 = expf(s0 - m), e1 = expf(s1 - m);
    float sw = wred_sum(e0 + e1);
    if (lw == 0) red_b[wid] = sw;
    __syncthreads();
    float inv = 1.f / (red_b[0] + red_b[1] + red_b[2] + red_b[3]);
    float* op = out + (size_t)(b * NT + t2 * 2 + task) * NR;
    op[tid]       = e0 * inv;
    op[256 + tid] = e1 * inv;
  }
}

// ---------------- launch ----------------
extern "C" void kernel_launch(void* const* d_in, const int* in_sizes, int n_in,
                              void* d_out, int out_size, void* d_ws, size_t ws_size,
                              hipStream_t stream)
{
  const float* rs   = (const float*)d_in[0];
  const float* ts   = (const float*)d_in[1];
  const float* r_w1 = (const float*)d_in[2];  const float* r_b1 = (const float*)d_in[3];
  const float* r_w2 = (const float*)d_in[4];  const float* r_b2 = (const float*)d_in[5];
  const float* t_w1 = (const float*)d_in[6];  const float* t_b1 = (const float*)d_in[7];
  const float* t_w2 = (const float*)d_in[8];  const float* t_b2 = (const float*)d_in[9];
  const float* wq   = (const float*)d_in[10]; const float* bq   = (const float*)d_in[11];
  const float* wk   = (const float*)d_in[12]; const float* bk   = (const float*)d_in[13];
  const float* wv   = (const float*)d_in[14]; const float* bv   = (const float*)d_in[15];
  const float* wo   = (const float*)d_in[16]; const float* bo   = (const float*)d_in[17];
  const float* a_w1 = (const float*)d_in[18]; const float* a_b1 = (const float*)d_in[19];
  const float* a_w2 = (const float*)d_in[20]; const float* a_b2 = (const float*)d_in[21];
  const float* a_w3 = (const float*)d_in[22]; const float* a_b3 = (const float*)d_in[23];

  float* wsf   = (float*)d_ws;
  float* kbuf  = wsf;                                   // 32*512*64
  float* vbuf  = kbuf  + (size_t)NB * NR * 64;          // 32*512*64
  float* rpbuf = vbuf  + (size_t)NB * NR * 64;          // 32*512*64
  float* qbuf  = rpbuf + (size_t)NB * NR * 64;          // 32*128*64
  float* tpbuf = qbuf  + (size_t)NB * NT * 64;          // 32*128*64
  unsigned short* w2f = (unsigned short*)(tpbuf + (size_t)NB * NT * 64); // 8*64*8

  enc_kernel<<<dim3(641), dim3(256), 0, stream>>>(
      rs, ts, r_w1, r_b1, r_w2, r_b2, t_w1, t_b1, t_w2, t_b2,
      wq, bq, wk, bk, wv, bv, a_w1, a_w2, kbuf, vbuf, rpbuf, qbuf, w2f);

  attn_kernel<<<dim3(2048), dim3(256), 0, stream>>>(
      qbuf, kbuf, vbuf, wo, bo, a_w1, a_b1, tpbuf);

  pair_kernel<<<dim3(2048), dim3(256), 0, stream>>>(
      tpbuf, rpbuf, w2f, a_b2, a_w3, (float*)d_out);
}

// Round 8
// 213.030 us; speedup vs baseline: 1.4170x; 1.0425x over previous
//
#include <hip/hip_runtime.h>
#include <hip/hip_bf16.h>
#include <math.h>

#define NB 32
#define NR 512
#define NT 128

typedef __attribute__((ext_vector_type(8))) short short8;
typedef __attribute__((ext_vector_type(4))) float f32x4;
typedef __attribute__((ext_vector_type(2))) float f32x2;

// ---------------- wave (64-lane) reductions ----------------
__device__ __forceinline__ float wred_max(float v){
#pragma unroll
  for (int o = 32; o > 0; o >>= 1) v = fmaxf(v, __shfl_xor(v, o));
  return v;
}
__device__ __forceinline__ float wred_sum(float v){
#pragma unroll
  for (int o = 32; o > 0; o >>= 1) v += __shfl_xor(v, o);
  return v;
}
__device__ __forceinline__ float dot4(float4 a, float4 b){
  return a.x * b.x + a.y * b.y + a.z * b.z + a.w * b.w;
}

// 16-lane-group sum via DPP row_shr (VALU-only, no LDS). Result in n16==15.
__device__ __forceinline__ float dpp_add16(float s){
  int x;
  x = __builtin_amdgcn_update_dpp(0, __float_as_int(s), 0x111, 0xf, 0xf, true);
  s += __int_as_float(x);   // row_shr:1
  x = __builtin_amdgcn_update_dpp(0, __float_as_int(s), 0x112, 0xf, 0xf, true);
  s += __int_as_float(x);   // row_shr:2
  x = __builtin_amdgcn_update_dpp(0, __float_as_int(s), 0x114, 0xf, 0xf, true);
  s += __int_as_float(x);   // row_shr:4
  x = __builtin_amdgcn_update_dpp(0, __float_as_int(s), 0x118, 0xf, 0xf, true);
  s += __int_as_float(x);   // row_shr:8
  return s;
}

// ---------------- encoder kernel v2: 32 rows/block (641 blocks) ------------
__global__ __launch_bounds__(256) void enc_kernel(
    const float* __restrict__ rs, const float* __restrict__ ts,
    const float* __restrict__ r_w1, const float* __restrict__ r_b1,
    const float* __restrict__ r_w2, const float* __restrict__ r_b2,
    const float* __restrict__ t_w1, const float* __restrict__ t_b1,
    const float* __restrict__ t_w2, const float* __restrict__ t_b2,
    const float* __restrict__ wq, const float* __restrict__ bq,
    const float* __restrict__ wk, const float* __restrict__ bk,
    const float* __restrict__ wv, const float* __restrict__ bv,
    const float* __restrict__ a_w1, const float* __restrict__ a_w2,
    float* __restrict__ kbuf, float* __restrict__ vbuf,
    float* __restrict__ rpbuf, float* __restrict__ qbuf,
    unsigned short* __restrict__ w2f)
{
  __shared__ float w1s[448];
  __shared__ float wss[4096];
  __shared__ float h_s[32 * 66];
  __shared__ float rf_s[32 * 66];

  const int tid = threadIdx.x;
  const int blk = blockIdx.x;

  if (blk == 640) {        // fused prep: split a_w2 into hi/lo bf16 B-frags
    if (tid < 64) {
      int l = tid, n16 = l & 15, g = l >> 4;
      for (int f = 0; f < 8; ++f) {
        int ntile = f & 1, ks = (f >> 1) & 1, part = f >> 2;
        for (int j = 0; j < 8; ++j) {
          int k = ks * 32 + g * 8 + j;
          int n = ntile * 16 + n16;
          unsigned wb = __float_as_uint(a_w2[k * 32 + n]);
          unsigned hib = wb & 0xffff0000u;
          float lof = __uint_as_float(wb) - __uint_as_float(hib);
          unsigned lob = __float_as_uint(lof) & 0xffff0000u;
          w2f[((size_t)f * 64 + l) * 8 + j] =
              (unsigned short)((part == 0 ? hib : lob) >> 16);
        }
      }
    }
    return;
  }

  const int rb = tid >> 3, t8 = tid & 7;
  const bool robot = blk < 512;

  if (robot) {
    if (tid < 112) ((float4*)w1s)[tid] = ((const float4*)r_w1)[tid];
#pragma unroll
    for (int c = 0; c < 4; ++c)
      ((float4*)wss)[c * 256 + tid] = ((const float4*)r_w2)[c * 256 + tid];
  } else {
    if (tid < 96) ((float4*)w1s)[tid] = ((const float4*)t_w1)[tid];
#pragma unroll
    for (int c = 0; c < 4; ++c)
      ((float4*)wss)[c * 256 + tid] = ((const float4*)t_w2)[c * 256 + tid];
  }

  int g, K1;
  const float* xin; const float* b1; const float* b2;
  if (robot) { g = blk * 32 + rb;          K1 = 7; xin = rs + (size_t)g * 7; b1 = r_b1; b2 = r_b2; }
  else       { g = (blk - 512) * 32 + rb;  K1 = 6; xin = ts + (size_t)g * 6; b1 = t_b1; b2 = t_b2; }

  float x[7];
  for (int k = 0; k < K1; ++k) x[k] = xin[k];
  __syncthreads();

  {
    float acc[8];
#pragma unroll
    for (int jj = 0; jj < 8; ++jj) acc[jj] = b1[t8 * 8 + jj];
    for (int k = 0; k < K1; ++k) {
      float xv = x[k];
#pragma unroll
      for (int jj = 0; jj < 8; ++jj) acc[jj] += xv * w1s[k * 64 + t8 * 8 + jj];
    }
#pragma unroll
    for (int jj = 0; jj < 8; ++jj) h_s[rb * 66 + t8 * 8 + jj] = fmaxf(acc[jj], 0.f);
  }
  __syncthreads();

  {
    float acc[8];
#pragma unroll
    for (int jj = 0; jj < 8; ++jj) acc[jj] = b2[t8 * 8 + jj];
    for (int k = 0; k < 64; ++k) {
      float hv = h_s[rb * 66 + k];
      const float4* wr = (const float4*)(wss + k * 64 + t8 * 8);
#pragma unroll
      for (int j4 = 0; j4 < 2; ++j4) {
        float4 w = wr[j4];
        acc[j4 * 4 + 0] += hv * w.x; acc[j4 * 4 + 1] += hv * w.y;
        acc[j4 * 4 + 2] += hv * w.z; acc[j4 * 4 + 3] += hv * w.w;
      }
    }
#pragma unroll
    for (int jj = 0; jj < 8; ++jj) rf_s[rb * 66 + t8 * 8 + jj] = fmaxf(acc[jj], 0.f);
  }

  const float* wp[3]; const float* bp[3]; float* op[3]; int npass;
  if (robot) {
    wp[0] = wk; bp[0] = bk;      op[0] = kbuf;
    wp[1] = wv; bp[1] = bv;      op[1] = vbuf;
    wp[2] = a_w1 + 64 * 64; bp[2] = nullptr; op[2] = rpbuf;
    npass = 3;
  } else {
    wp[0] = wq; bp[0] = bq; op[0] = qbuf; npass = 1;
  }
  for (int p = 0; p < npass; ++p) {
    __syncthreads();
#pragma unroll
    for (int c = 0; c < 4; ++c)
      ((float4*)wss)[c * 256 + tid] = ((const float4*)wp[p])[c * 256 + tid];
    __syncthreads();
    float acc[8];
#pragma unroll
    for (int jj = 0; jj < 8; ++jj) acc[jj] = bp[p] ? bp[p][t8 * 8 + jj] : 0.f;
    for (int k = 0; k < 64; ++k) {
      float hv = rf_s[rb * 66 + k];
      const float4* wr = (const float4*)(wss + k * 64 + t8 * 8);
#pragma unroll
      for (int j4 = 0; j4 < 2; ++j4) {
        float4 w = wr[j4];
        acc[j4 * 4 + 0] += hv * w.x; acc[j4 * 4 + 1] += hv * w.y;
        acc[j4 * 4 + 2] += hv * w.z; acc[j4 * 4 + 3] += hv * w.w;
      }
    }
    float4* o4 = (float4*)(op[p] + (size_t)g * 64 + t8 * 8);
    o4[0] = make_float4(acc[0], acc[1], acc[2], acc[3]);
    o4[1] = make_float4(acc[4], acc[5], acc[6], acc[7]);
  }
}

// ---------------- attention kernel v2 (unchanged) --------------------------
#define LGS 520
__global__ __launch_bounds__(256, 4) void attn_kernel(
    const float* __restrict__ qbuf, const float* __restrict__ kbuf,
    const float* __restrict__ vbuf,
    const float* __restrict__ wo, const float* __restrict__ bo,
    const float* __restrict__ a_w1, const float* __restrict__ a_b1,
    float* __restrict__ tpbuf)
{
  __shared__ float qt_s[2 * 64];
  __shared__ float lg[2][4 * LGS];
  __shared__ float inv_s[8];
  __shared__ float cp[4][2 * 64];
  __shared__ float ctx_s[2 * 64];

  const int tid = threadIdx.x;
  const int jj = blockIdx.x & 31;
  const int b  = (jj & 7) * 4 + (jj >> 3);
  const int t0 = (blockIdx.x >> 5) * 2;

  if (tid < 32) {
    int tt = tid >> 4, i4 = tid & 15;
    float4 v = ((const float4*)(qbuf + (size_t)(b * NT + t0 + tt) * 64))[i4];
    v.x *= 0.25f; v.y *= 0.25f; v.z *= 0.25f; v.w *= 0.25f;
    ((float4*)qt_s)[tid] = v;
  }
  __syncthreads();

  {
    const int h = tid & 3;
    const int r0 = tid >> 2;
    const float4* q0 = (const float4*)(qt_s + h * 16);
    const float4* q1 = (const float4*)(qt_s + 64 + h * 16);
    float4 q0a = q0[0], q0b = q0[1], q0c = q0[2], q0d = q0[3];
    float4 q1a = q1[0], q1b = q1[1], q1c = q1[2], q1d = q1[3];
    const float* kb0 = kbuf + (size_t)b * NR * 64 + h * 16;
    for (int it = 0; it < 8; ++it) {
      int r = r0 + it * 64;
      const float4* k4 = (const float4*)(kb0 + (size_t)r * 64);
      float4 ka = k4[0], kb = k4[1], kc = k4[2], kd = k4[3];
      float s0 = dot4(q0a, ka) + dot4(q0b, kb) + dot4(q0c, kc) + dot4(q0d, kd);
      float s1 = dot4(q1a, ka) + dot4(q1b, kb) + dot4(q1c, kc) + dot4(q1d, kd);
      lg[0][h * LGS + r] = s0;
      lg[1][h * LGS + r] = s1;
    }
  }
  __syncthreads();

  {
    int w = tid >> 6, lane = tid & 63;
    for (int p = 0; p < 2; ++p) {
      int pr = w * 2 + p, tt = pr >> 2, hh = pr & 3;
      float* row = &lg[tt][hh * LGS];
      float v0[8];
#pragma unroll
      for (int u = 0; u < 8; ++u) v0[u] = row[u * 64 + lane];
      float m = v0[0];
#pragma unroll
      for (int u = 1; u < 8; ++u) m = fmaxf(m, v0[u]);
      m = wred_max(m);
      float s = 0.f;
#pragma unroll
      for (int u = 0; u < 8; ++u) {
        float e = expf(v0[u] - m);
        row[u * 64 + lane] = e;
        s += e;
      }
      s = wred_sum(s);
      if (lane == 0) inv_s[tt * 4 + hh] = 1.f / s;
    }
  }
  __syncthreads();

  {
    int od = tid & 63, ch = tid >> 6;
    int h = od >> 4, d = od & 15;
    float acc0 = 0.f, acc1 = 0.f;
    const float* vptr = vbuf + (size_t)b * NR * 64 + h * 16 + d;
#pragma unroll 4
    for (int u = 0; u < 128; ++u) {
      int r = ch * 128 + u;
      float vv = vptr[(size_t)r * 64];
      acc0 += lg[0][h * LGS + r] * vv;
      acc1 += lg[1][h * LGS + r] * vv;
    }
    cp[ch][od]      = acc0;
    cp[ch][64 + od] = acc1;
  }
  __syncthreads();
  if (tid < 128) {
    int od = tid & 63, h = od >> 4;
    ctx_s[tid] = (cp[0][tid] + cp[1][tid] + cp[2][tid] + cp[3][tid]) *
                 inv_s[(tid >> 6) * 4 + h];
  }
  __syncthreads();

  {
    int jd = tid & 63, kc = tid >> 6;
    float p0 = 0.f, p1 = 0.f;
    for (int k = 0; k < 16; ++k) {
      float w = wo[(kc * 16 + k) * 64 + jd];
      p0 += ctx_s[kc * 16 + k] * w;
      p1 += ctx_s[64 + kc * 16 + k] * w;
    }
    cp[kc][jd]      = p0;
    cp[kc][64 + jd] = p1;
  }
  __syncthreads();
  if (tid < 128) {
    int jd = tid & 63;
    qt_s[tid] = cp[0][tid] + cp[1][tid] + cp[2][tid] + cp[3][tid] + bo[jd];
  }
  __syncthreads();

  {
    int jd = tid & 63, kc = tid >> 6;
    float p0 = 0.f, p1 = 0.f;
    for (int k = 0; k < 16; ++k) {
      float w = a_w1[(kc * 16 + k) * 64 + jd];
      p0 += qt_s[kc * 16 + k] * w;
      p1 += qt_s[64 + kc * 16 + k] * w;
    }
    cp[kc][jd]      = p0;
    cp[kc][64 + jd] = p1;
  }
  __syncthreads();
  if (tid < 128) {
    int jd = tid & 63;
    tpbuf[(size_t)(b * NT + t0) * 64 + tid] =
        cp[0][tid] + cp[1][tid] + cp[2][tid] + cp[3][tid] + a_b1[jd];
  }
}

// ---------------- pairwise allocation kernel (v6) --------------------------
// v5b + (a) DPP-based epilogue reduction (no ds_swizzle in hot loop),
//       (b) RNE hi/lo split via v_cvt_pk_bf16_f32 (__float22bfloat162_rn).
__device__ __forceinline__ void mk2(f32x2 r, f32x2 t,
                                    unsigned* h, unsigned* l)
{
  f32x2 x = r + t;                                     // v_pk_add_f32
  x = __builtin_elementwise_max(x, (f32x2){0.f, 0.f}); // v_pk_max_f32
  __hip_bfloat162 hb = __float22bfloat162_rn(make_float2(x.x, x.y));
  unsigned hh; __builtin_memcpy(&hh, &hb, 4);
  f32x2 hf;
  hf.x = __int_as_float((int)(hh << 16));
  hf.y = __int_as_float((int)(hh & 0xffff0000u));
  f32x2 e = x - hf;                                    // exact residual
  __hip_bfloat162 lb = __float22bfloat162_rn(make_float2(e.x, e.y));
  unsigned ll; __builtin_memcpy(&ll, &lb, 4);
  *h = hh; *l = ll;
}

__device__ __forceinline__ void mk_frags(float4 ra, float4 rb,
                                         float4 ta, float4 tb,
                                         short8* Ah, short8* Al)
{
  unsigned h0, h1, h2, h3, l0, l1, l2, l3;
  mk2((f32x2){ra.x, ra.y}, (f32x2){ta.x, ta.y}, &h0, &l0);
  mk2((f32x2){ra.z, ra.w}, (f32x2){ta.z, ta.w}, &h1, &l1);
  mk2((f32x2){rb.x, rb.y}, (f32x2){tb.x, tb.y}, &h2, &l2);
  mk2((f32x2){rb.z, rb.w}, (f32x2){tb.z, tb.w}, &h3, &l3);
  *Ah = __builtin_bit_cast(short8, make_int4((int)h0, (int)h1, (int)h2, (int)h3));
  *Al = __builtin_bit_cast(short8, make_int4((int)l0, (int)l1, (int)l2, (int)l3));
}

__global__ __launch_bounds__(256) void pair_kernel(
    const float* __restrict__ tpbuf, const float* __restrict__ rpbuf,
    const unsigned short* __restrict__ w2f,
    const float* __restrict__ a_b2, const float* __restrict__ a_w3,
    float* __restrict__ out)
{
  __shared__ float scores_s[2][512];
  __shared__ float red_a[4];
  __shared__ float red_b[4];

  const int tid = threadIdx.x;
  const int jj = blockIdx.x & 31;
  const int b  = (jj & 7) * 4 + (jj >> 3);   // XCD-locality swizzle
  const int t2 = blockIdx.x >> 5;            // task pair [0,64)
  const int wave = tid >> 6, lane = tid & 63;
  const int n16 = lane & 15, g = lane >> 4;

  short8 B[8];
#pragma unroll
  for (int f = 0; f < 8; ++f)
    B[f] = __builtin_bit_cast(short8, ((const int4*)w2f)[f * 64 + lane]);

  const float* tpA = tpbuf + (size_t)(b * NT + t2 * 2) * 64 + g * 8;
  const float* tpB = tpA + 64;
  float4 tA0a = *(const float4*)(tpA),      tA0b = *(const float4*)(tpA + 4);
  float4 tA1a = *(const float4*)(tpA + 32), tA1b = *(const float4*)(tpA + 36);
  float4 tB0a = *(const float4*)(tpB),      tB0b = *(const float4*)(tpB + 4);
  float4 tB1a = *(const float4*)(tpB + 32), tB1b = *(const float4*)(tpB + 36);

  float b20 = a_b2[n16], b21 = a_b2[16 + n16];
  float w30 = a_w3[n16], w31 = a_w3[16 + n16];

  const float* rpb = rpbuf + (size_t)b * NR * 64 + g * 8;

  // prefetch mt = 0
  const float4* rp0 = (const float4*)(rpb + (size_t)(wave * 128 + n16) * 64);
  float4 ra0 = rp0[0], rb0 = rp0[1], ra1 = rp0[8], rb1 = rp0[9];

#pragma unroll
  for (int mt = 0; mt < 8; ++mt) {
    float4 na0, nb0, na1, nb1;
    if (mt < 7) {   // prefetch next mt while this one computes
      const float4* rpn =
          (const float4*)(rpb + (size_t)(wave * 128 + (mt + 1) * 16 + n16) * 64);
      na0 = rpn[0]; nb0 = rpn[1]; na1 = rpn[8]; nb1 = rpn[9];
    }

#pragma unroll
    for (int task = 0; task < 2; ++task) {
      short8 Ah0, Al0, Ah1, Al1;
      if (task == 0) {
        mk_frags(ra0, rb0, tA0a, tA0b, &Ah0, &Al0);
        mk_frags(ra1, rb1, tA1a, tA1b, &Ah1, &Al1);
      } else {
        mk_frags(ra0, rb0, tB0a, tB0b, &Ah0, &Al0);
        mk_frags(ra1, rb1, tB1a, tB1b, &Ah1, &Al1);
      }
      f32x4 acc0 = (f32x4){b20, b20, b20, b20};
      f32x4 acc1 = (f32x4){b21, b21, b21, b21};
      acc0 = __builtin_amdgcn_mfma_f32_16x16x32_bf16(Ah0, B[0], acc0, 0, 0, 0);
      acc1 = __builtin_amdgcn_mfma_f32_16x16x32_bf16(Ah0, B[1], acc1, 0, 0, 0);
      acc0 = __builtin_amdgcn_mfma_f32_16x16x32_bf16(Al0, B[0], acc0, 0, 0, 0);
      acc1 = __builtin_amdgcn_mfma_f32_16x16x32_bf16(Al0, B[1], acc1, 0, 0, 0);
      acc0 = __builtin_amdgcn_mfma_f32_16x16x32_bf16(Ah0, B[4], acc0, 0, 0, 0);
      acc1 = __builtin_amdgcn_mfma_f32_16x16x32_bf16(Ah0, B[5], acc1, 0, 0, 0);
      acc0 = __builtin_amdgcn_mfma_f32_16x16x32_bf16(Ah1, B[2], acc0, 0, 0, 0);
      acc1 = __builtin_amdgcn_mfma_f32_16x16x32_bf16(Ah1, B[3], acc1, 0, 0, 0);
      acc0 = __builtin_amdgcn_mfma_f32_16x16x32_bf16(Al1, B[2], acc0, 0, 0, 0);
      acc1 = __builtin_amdgcn_mfma_f32_16x16x32_bf16(Al1, B[3], acc1, 0, 0, 0);
      acc0 = __builtin_amdgcn_mfma_f32_16x16x32_bf16(Ah1, B[6], acc0, 0, 0, 0);
      acc1 = __builtin_amdgcn_mfma_f32_16x16x32_bf16(Ah1, B[7], acc1, 0, 0, 0);
#pragma unroll
      for (int reg = 0; reg < 4; ++reg) {
        float s = fmaxf(acc0[reg], 0.f) * w30 + fmaxf(acc1[reg], 0.f) * w31;
        s = dpp_add16(s);                 // VALU-only 16-lane reduction
        if (n16 == 15)
          scores_s[task][wave * 128 + mt * 16 + g * 4 + reg] = s;
      }
    }
    ra0 = na0; rb0 = nb0; ra1 = na1; rb1 = nb1;
  }
  __syncthreads();

  const int lw = tid & 63, wid = tid >> 6;
  for (int task = 0; task < 2; ++task) {
    float s0 = scores_s[task][tid], s1 = scores_s[task][tid + 256];
    float mw = wred_max(fmaxf(s0, s1));
    if (lw == 0) red_a[wid] = mw;
    __syncthreads();
    float m = fmaxf(fmaxf(red_a[0], red_a[1]), fmaxf(red_a[2], red_a[3]));
    float e0 = expf(s0 - m), e1 = expf(s1 - m);
    float sw = wred_sum(e0 + e1);
    if (lw == 0) red_b[wid] = sw;
    __syncthreads();
    float inv = 1.f / (red_b[0] + red_b[1] + red_b[2] + red_b[3]);
    float* op = out + (size_t)(b * NT + t2 * 2 + task) * NR;
    op[tid]       = e0 * inv;
    op[256 + tid] = e1 * inv;
  }
}

// ---------------- launch ----------------
extern "C" void kernel_launch(void* const* d_in, const int* in_sizes, int n_in,
                              void* d_out, int out_size, void* d_ws, size_t ws_size,
                              hipStream_t stream)
{
  const float* rs   = (const float*)d_in[0];
  const float* ts   = (const float*)d_in[1];
  const float* r_w1 = (const float*)d_in[2];  const float* r_b1 = (const float*)d_in[3];
  const float* r_w2 = (const float*)d_in[4];  const float* r_b2 = (const float*)d_in[5];
  const float* t_w1 = (const float*)d_in[6];  const float* t_b1 = (const float*)d_in[7];
  const float* t_w2 = (const float*)d_in[8];  const float* t_b2 = (const float*)d_in[9];
  const float* wq   = (const float*)d_in[10]; const float* bq   = (const float*)d_in[11];
  const float* wk   = (const float*)d_in[12]; const float* bk   = (const float*)d_in[13];
  const float* wv   = (const float*)d_in[14]; const float* bv   = (const float*)d_in[15];
  const float* wo   = (const float*)d_in[16]; const float* bo   = (const float*)d_in[17];
  const float* a_w1 = (const float*)d_in[18]; const float* a_b1 = (const float*)d_in[19];
  const float* a_w2 = (const float*)d_in[20]; const float* a_b2 = (const float*)d_in[21];
  const float* a_w3 = (const float*)d_in[22]; const float* a_b3 = (const float*)d_in[23];

  float* wsf   = (float*)d_ws;
  float* kbuf  = wsf;                                   // 32*512*64
  float* vbuf  = kbuf  + (size_t)NB * NR * 64;          // 32*512*64
  float* rpbuf = vbuf  + (size_t)NB * NR * 64;          // 32*512*64
  float* qbuf  = rpbuf + (size_t)NB * NR * 64;          // 32*128*64
  float* tpbuf = qbuf  + (size_t)NB * NT * 64;          // 32*128*64
  unsigned short* w2f = (unsigned short*)(tpbuf + (size_t)NB * NT * 64); // 8*64*8

  enc_kernel<<<dim3(641), dim3(256), 0, stream>>>(
      rs, ts, r_w1, r_b1, r_w2, r_b2, t_w1, t_b1, t_w2, t_b2,
      wq, bq, wk, bk, wv, bv, a_w1, a_w2, kbuf, vbuf, rpbuf, qbuf, w2f);

  attn_kernel<<<dim3(2048), dim3(256), 0, stream>>>(
      qbuf, kbuf, vbuf, wo, bo, a_w1, a_b1, tpbuf);

  pair_kernel<<<dim3(2048), dim3(256), 0, stream>>>(
      tpbuf, rpbuf, w2f, a_b2, a_w3, (float*)d_out);
}

// Round 9
// 207.259 us; speedup vs baseline: 1.4564x; 1.0278x over previous
//
#include <hip/hip_runtime.h>
#include <hip/hip_bf16.h>
#include <math.h>

#define NB 32
#define NR 512
#define NT 128

typedef __attribute__((ext_vector_type(8))) short short8;
typedef __attribute__((ext_vector_type(4))) float f32x4;
typedef __attribute__((ext_vector_type(2))) float f32x2;

// ---------------- wave (64-lane) reductions ----------------
__device__ __forceinline__ float wred_max(float v){
#pragma unroll
  for (int o = 32; o > 0; o >>= 1) v = fmaxf(v, __shfl_xor(v, o));
  return v;
}
__device__ __forceinline__ float wred_sum(float v){
#pragma unroll
  for (int o = 32; o > 0; o >>= 1) v += __shfl_xor(v, o);
  return v;
}
__device__ __forceinline__ float dot4(float4 a, float4 b){
  return a.x * b.x + a.y * b.y + a.z * b.z + a.w * b.w;
}

// 16-lane-group sum via DPP row_shr (VALU-only, no LDS). Result in n16==15.
__device__ __forceinline__ float dpp_add16(float s){
  int x;
  x = __builtin_amdgcn_update_dpp(0, __float_as_int(s), 0x111, 0xf, 0xf, true);
  s += __int_as_float(x);   // row_shr:1
  x = __builtin_amdgcn_update_dpp(0, __float_as_int(s), 0x112, 0xf, 0xf, true);
  s += __int_as_float(x);   // row_shr:2
  x = __builtin_amdgcn_update_dpp(0, __float_as_int(s), 0x114, 0xf, 0xf, true);
  s += __int_as_float(x);   // row_shr:4
  x = __builtin_amdgcn_update_dpp(0, __float_as_int(s), 0x118, 0xf, 0xf, true);
  s += __int_as_float(x);   // row_shr:8
  return s;
}

// ---------------- encoder kernel v2 (unchanged, 641 blocks) ----------------
__global__ __launch_bounds__(256) void enc_kernel(
    const float* __restrict__ rs, const float* __restrict__ ts,
    const float* __restrict__ r_w1, const float* __restrict__ r_b1,
    const float* __restrict__ r_w2, const float* __restrict__ r_b2,
    const float* __restrict__ t_w1, const float* __restrict__ t_b1,
    const float* __restrict__ t_w2, const float* __restrict__ t_b2,
    const float* __restrict__ wq, const float* __restrict__ bq,
    const float* __restrict__ wk, const float* __restrict__ bk,
    const float* __restrict__ wv, const float* __restrict__ bv,
    const float* __restrict__ a_w1, const float* __restrict__ a_w2,
    float* __restrict__ kbuf, float* __restrict__ vbuf,
    float* __restrict__ rpbuf, float* __restrict__ qbuf,
    unsigned short* __restrict__ w2f)
{
  __shared__ float w1s[448];
  __shared__ float wss[4096];
  __shared__ float h_s[32 * 66];
  __shared__ float rf_s[32 * 66];

  const int tid = threadIdx.x;
  const int blk = blockIdx.x;

  if (blk == 640) {        // fused prep: split a_w2 into hi/lo bf16 B-frags
    if (tid < 64) {
      int l = tid, n16 = l & 15, g = l >> 4;
      for (int f = 0; f < 8; ++f) {
        int ntile = f & 1, ks = (f >> 1) & 1, part = f >> 2;
        for (int j = 0; j < 8; ++j) {
          int k = ks * 32 + g * 8 + j;
          int n = ntile * 16 + n16;
          unsigned wb = __float_as_uint(a_w2[k * 32 + n]);
          unsigned hib = wb & 0xffff0000u;
          float lof = __uint_as_float(wb) - __uint_as_float(hib);
          unsigned lob = __float_as_uint(lof) & 0xffff0000u;
          w2f[((size_t)f * 64 + l) * 8 + j] =
              (unsigned short)((part == 0 ? hib : lob) >> 16);
        }
      }
    }
    return;
  }

  const int rb = tid >> 3, t8 = tid & 7;
  const bool robot = blk < 512;

  if (robot) {
    if (tid < 112) ((float4*)w1s)[tid] = ((const float4*)r_w1)[tid];
#pragma unroll
    for (int c = 0; c < 4; ++c)
      ((float4*)wss)[c * 256 + tid] = ((const float4*)r_w2)[c * 256 + tid];
  } else {
    if (tid < 96) ((float4*)w1s)[tid] = ((const float4*)t_w1)[tid];
#pragma unroll
    for (int c = 0; c < 4; ++c)
      ((float4*)wss)[c * 256 + tid] = ((const float4*)t_w2)[c * 256 + tid];
  }

  int g, K1;
  const float* xin; const float* b1; const float* b2;
  if (robot) { g = blk * 32 + rb;          K1 = 7; xin = rs + (size_t)g * 7; b1 = r_b1; b2 = r_b2; }
  else       { g = (blk - 512) * 32 + rb;  K1 = 6; xin = ts + (size_t)g * 6; b1 = t_b1; b2 = t_b2; }

  float x[7];
  for (int k = 0; k < K1; ++k) x[k] = xin[k];
  __syncthreads();

  {
    float acc[8];
#pragma unroll
    for (int jj = 0; jj < 8; ++jj) acc[jj] = b1[t8 * 8 + jj];
    for (int k = 0; k < K1; ++k) {
      float xv = x[k];
#pragma unroll
      for (int jj = 0; jj < 8; ++jj) acc[jj] += xv * w1s[k * 64 + t8 * 8 + jj];
    }
#pragma unroll
    for (int jj = 0; jj < 8; ++jj) h_s[rb * 66 + t8 * 8 + jj] = fmaxf(acc[jj], 0.f);
  }
  __syncthreads();

  {
    float acc[8];
#pragma unroll
    for (int jj = 0; jj < 8; ++jj) acc[jj] = b2[t8 * 8 + jj];
    for (int k = 0; k < 64; ++k) {
      float hv = h_s[rb * 66 + k];
      const float4* wr = (const float4*)(wss + k * 64 + t8 * 8);
#pragma unroll
      for (int j4 = 0; j4 < 2; ++j4) {
        float4 w = wr[j4];
        acc[j4 * 4 + 0] += hv * w.x; acc[j4 * 4 + 1] += hv * w.y;
        acc[j4 * 4 + 2] += hv * w.z; acc[j4 * 4 + 3] += hv * w.w;
      }
    }
#pragma unroll
    for (int jj = 0; jj < 8; ++jj) rf_s[rb * 66 + t8 * 8 + jj] = fmaxf(acc[jj], 0.f);
  }

  const float* wp[3]; const float* bp[3]; float* op[3]; int npass;
  if (robot) {
    wp[0] = wk; bp[0] = bk;      op[0] = kbuf;
    wp[1] = wv; bp[1] = bv;      op[1] = vbuf;
    wp[2] = a_w1 + 64 * 64; bp[2] = nullptr; op[2] = rpbuf;
    npass = 3;
  } else {
    wp[0] = wq; bp[0] = bq; op[0] = qbuf; npass = 1;
  }
  for (int p = 0; p < npass; ++p) {
    __syncthreads();
#pragma unroll
    for (int c = 0; c < 4; ++c)
      ((float4*)wss)[c * 256 + tid] = ((const float4*)wp[p])[c * 256 + tid];
    __syncthreads();
    float acc[8];
#pragma unroll
    for (int jj = 0; jj < 8; ++jj) acc[jj] = bp[p] ? bp[p][t8 * 8 + jj] : 0.f;
    for (int k = 0; k < 64; ++k) {
      float hv = rf_s[rb * 66 + k];
      const float4* wr = (const float4*)(wss + k * 64 + t8 * 8);
#pragma unroll
      for (int j4 = 0; j4 < 2; ++j4) {
        float4 w = wr[j4];
        acc[j4 * 4 + 0] += hv * w.x; acc[j4 * 4 + 1] += hv * w.y;
        acc[j4 * 4 + 2] += hv * w.z; acc[j4 * 4 + 3] += hv * w.w;
      }
    }
    float4* o4 = (float4*)(op[p] + (size_t)g * 64 + t8 * 8);
    o4[0] = make_float4(acc[0], acc[1], acc[2], acc[3]);
    o4[1] = make_float4(acc[4], acc[5], acc[6], acc[7]);
  }
}

// ---------------- split helpers (pair) -------------------------------------
__device__ __forceinline__ void mk2(f32x2 r, f32x2 t,
                                    unsigned* h, unsigned* l)
{
  f32x2 x = r + t;                                     // v_pk_add_f32
  x = __builtin_elementwise_max(x, (f32x2){0.f, 0.f}); // v_pk_max_f32
  __hip_bfloat162 hb = __float22bfloat162_rn(make_float2(x.x, x.y));
  unsigned hh; __builtin_memcpy(&hh, &hb, 4);
  f32x2 hf;
  hf.x = __int_as_float((int)(hh << 16));
  hf.y = __int_as_float((int)(hh & 0xffff0000u));
  f32x2 e = x - hf;                                    // exact residual
  __hip_bfloat162 lb = __float22bfloat162_rn(make_float2(e.x, e.y));
  unsigned ll; __builtin_memcpy(&ll, &lb, 4);
  *h = hh; *l = ll;
}

__device__ __forceinline__ void mk_frags(float4 ra, float4 rb,
                                         float4 ta, float4 tb,
                                         short8* Ah, short8* Al)
{
  unsigned h0, h1, h2, h3, l0, l1, l2, l3;
  mk2((f32x2){ra.x, ra.y}, (f32x2){ta.x, ta.y}, &h0, &l0);
  mk2((f32x2){ra.z, ra.w}, (f32x2){ta.z, ta.w}, &h1, &l1);
  mk2((f32x2){rb.x, rb.y}, (f32x2){tb.x, tb.y}, &h2, &l2);
  mk2((f32x2){rb.z, rb.w}, (f32x2){tb.z, tb.w}, &h3, &l3);
  *Ah = __builtin_bit_cast(short8, make_int4((int)h0, (int)h1, (int)h2, (int)h3));
  *Al = __builtin_bit_cast(short8, make_int4((int)l0, (int)l1, (int)l2, (int)l3));
}

// ---------------- fused attention + pairwise kernel ------------------------
// 2048 blocks = (b, task-pair), 256 thr. attn v2 phases A-E (tp -> LDS),
// then pair v6 body consuming tp from LDS. No tpbuf round-trip, one less
// launch; latency-bound attn phases overlap VALU-bound pair phases across
// blocks on the same CU.
#define LGS 520
__global__ __launch_bounds__(256, 4) void attn_pair_kernel(
    const float* __restrict__ qbuf, const float* __restrict__ kbuf,
    const float* __restrict__ vbuf,
    const float* __restrict__ wo, const float* __restrict__ bo,
    const float* __restrict__ a_w1, const float* __restrict__ a_b1,
    const unsigned short* __restrict__ w2f,
    const float* __restrict__ a_b2, const float* __restrict__ a_w3,
    const float* __restrict__ rpbuf,
    float* __restrict__ out)
{
  __shared__ float qt_s[2 * 64];        // q in phase A, tf in phase D
  __shared__ float lg[2][4 * LGS];
  __shared__ float inv_s[8];
  __shared__ float cp[4][2 * 64];
  __shared__ float ctx_s[2 * 64];
  __shared__ float tp_f[2 * 64];        // attn output (tp rows, 2 tasks)
  __shared__ float scores_s[2][512];
  __shared__ float red_a[4];
  __shared__ float red_b[4];

  const int tid = threadIdx.x;
  const int jj = blockIdx.x & 31;
  const int b  = (jj & 7) * 4 + (jj >> 3);   // XCD-locality swizzle
  const int t0 = (blockIdx.x >> 5) * 2;      // 64 task-pairs

  // ---------- attn phase A: logits ----------
  if (tid < 32) {
    int tt = tid >> 4, i4 = tid & 15;
    float4 v = ((const float4*)(qbuf + (size_t)(b * NT + t0 + tt) * 64))[i4];
    v.x *= 0.25f; v.y *= 0.25f; v.z *= 0.25f; v.w *= 0.25f;   // 1/sqrt(16)
    ((float4*)qt_s)[tid] = v;
  }
  __syncthreads();

  {
    const int h = tid & 3;
    const int r0 = tid >> 2;
    const float4* q0 = (const float4*)(qt_s + h * 16);
    const float4* q1 = (const float4*)(qt_s + 64 + h * 16);
    float4 q0a = q0[0], q0b = q0[1], q0c = q0[2], q0d = q0[3];
    float4 q1a = q1[0], q1b = q1[1], q1c = q1[2], q1d = q1[3];
    const float* kb0 = kbuf + (size_t)b * NR * 64 + h * 16;
    for (int it = 0; it < 8; ++it) {
      int r = r0 + it * 64;
      const float4* k4 = (const float4*)(kb0 + (size_t)r * 64);
      float4 ka = k4[0], kb = k4[1], kc = k4[2], kd = k4[3];
      float s0 = dot4(q0a, ka) + dot4(q0b, kb) + dot4(q0c, kc) + dot4(q0d, kd);
      float s1 = dot4(q1a, ka) + dot4(q1b, kb) + dot4(q1c, kc) + dot4(q1d, kd);
      lg[0][h * LGS + r] = s0;
      lg[1][h * LGS + r] = s1;
    }
  }
  __syncthreads();

  // ---------- attn phase B: softmax ----------
  {
    int w = tid >> 6, lane = tid & 63;
    for (int p = 0; p < 2; ++p) {
      int pr = w * 2 + p, tt = pr >> 2, hh = pr & 3;
      float* row = &lg[tt][hh * LGS];
      float v0[8];
#pragma unroll
      for (int u = 0; u < 8; ++u) v0[u] = row[u * 64 + lane];
      float m = v0[0];
#pragma unroll
      for (int u = 1; u < 8; ++u) m = fmaxf(m, v0[u]);
      m = wred_max(m);
      float s = 0.f;
#pragma unroll
      for (int u = 0; u < 8; ++u) {
        float e = expf(v0[u] - m);
        row[u * 64 + lane] = e;
        s += e;
      }
      s = wred_sum(s);
      if (lane == 0) inv_s[tt * 4 + hh] = 1.f / s;
    }
  }
  __syncthreads();

  // ---------- attn phase C: ctx = p.v ----------
  {
    int od = tid & 63, ch = tid >> 6;
    int h = od >> 4, d = od & 15;
    float acc0 = 0.f, acc1 = 0.f;
    const float* vptr = vbuf + (size_t)b * NR * 64 + h * 16 + d;
#pragma unroll 4
    for (int u = 0; u < 128; ++u) {
      int r = ch * 128 + u;
      float vv = vptr[(size_t)r * 64];
      acc0 += lg[0][h * LGS + r] * vv;
      acc1 += lg[1][h * LGS + r] * vv;
    }
    cp[ch][od]      = acc0;
    cp[ch][64 + od] = acc1;
  }
  __syncthreads();
  if (tid < 128) {
    int od = tid & 63, h = od >> 4;
    ctx_s[tid] = (cp[0][tid] + cp[1][tid] + cp[2][tid] + cp[3][tid]) *
                 inv_s[(tid >> 6) * 4 + h];
  }
  __syncthreads();

  // ---------- attn phase D: tf = ctx @ wo + bo ----------
  {
    int jd = tid & 63, kc = tid >> 6;
    float p0 = 0.f, p1 = 0.f;
    for (int k = 0; k < 16; ++k) {
      float w = wo[(kc * 16 + k) * 64 + jd];
      p0 += ctx_s[kc * 16 + k] * w;
      p1 += ctx_s[64 + kc * 16 + k] * w;
    }
    cp[kc][jd]      = p0;
    cp[kc][64 + jd] = p1;
  }
  __syncthreads();
  if (tid < 128) {
    int jd = tid & 63;
    qt_s[tid] = cp[0][tid] + cp[1][tid] + cp[2][tid] + cp[3][tid] + bo[jd];
  }
  __syncthreads();

  // ---------- attn phase E: tp = tf @ a_w1[:64] + a_b1 -> LDS ----------
  {
    int jd = tid & 63, kc = tid >> 6;
    float p0 = 0.f, p1 = 0.f;
    for (int k = 0; k < 16; ++k) {
      float w = a_w1[(kc * 16 + k) * 64 + jd];
      p0 += qt_s[kc * 16 + k] * w;
      p1 += qt_s[64 + kc * 16 + k] * w;
    }
    cp[kc][jd]      = p0;
    cp[kc][64 + jd] = p1;
  }
  __syncthreads();
  if (tid < 128) {
    int jd = tid & 63;
    tp_f[tid] = cp[0][tid] + cp[1][tid] + cp[2][tid] + cp[3][tid] + a_b1[jd];
  }
  __syncthreads();

  // ---------- pair body (v6) ----------
  const int wave = tid >> 6, lane = tid & 63;
  const int n16 = lane & 15, g = lane >> 4;

  // B fragments loaded AFTER attn phases (L2-hot) to keep peak VGPR low
  short8 B[8];
#pragma unroll
  for (int f = 0; f < 8; ++f)
    B[f] = __builtin_bit_cast(short8, ((const int4*)w2f)[f * 64 + lane]);

  const float* tpA = tp_f + g * 8;
  const float* tpB = tp_f + 64 + g * 8;
  float4 tA0a = *(const float4*)(tpA),      tA0b = *(const float4*)(tpA + 4);
  float4 tA1a = *(const float4*)(tpA + 32), tA1b = *(const float4*)(tpA + 36);
  float4 tB0a = *(const float4*)(tpB),      tB0b = *(const float4*)(tpB + 4);
  float4 tB1a = *(const float4*)(tpB + 32), tB1b = *(const float4*)(tpB + 36);

  float b20 = a_b2[n16], b21 = a_b2[16 + n16];
  float w30 = a_w3[n16], w31 = a_w3[16 + n16];

  const float* rpb = rpbuf + (size_t)b * NR * 64 + g * 8;

  // prefetch mt = 0
  const float4* rp0 = (const float4*)(rpb + (size_t)(wave * 128 + n16) * 64);
  float4 ra0 = rp0[0], rb0 = rp0[1], ra1 = rp0[8], rb1 = rp0[9];

#pragma unroll
  for (int mt = 0; mt < 8; ++mt) {
    float4 na0, nb0, na1, nb1;
    if (mt < 7) {
      const float4* rpn =
          (const float4*)(rpb + (size_t)(wave * 128 + (mt + 1) * 16 + n16) * 64);
      na0 = rpn[0]; nb0 = rpn[1]; na1 = rpn[8]; nb1 = rpn[9];
    }

#pragma unroll
    for (int task = 0; task < 2; ++task) {
      short8 Ah0, Al0, Ah1, Al1;
      if (task == 0) {
        mk_frags(ra0, rb0, tA0a, tA0b, &Ah0, &Al0);
        mk_frags(ra1, rb1, tA1a, tA1b, &Ah1, &Al1);
      } else {
        mk_frags(ra0, rb0, tB0a, tB0b, &Ah0, &Al0);
        mk_frags(ra1, rb1, tB1a, tB1b, &Ah1, &Al1);
      }
      f32x4 acc0 = (f32x4){b20, b20, b20, b20};
      f32x4 acc1 = (f32x4){b21, b21, b21, b21};
      acc0 = __builtin_amdgcn_mfma_f32_16x16x32_bf16(Ah0, B[0], acc0, 0, 0, 0);
      acc1 = __builtin_amdgcn_mfma_f32_16x16x32_bf16(Ah0, B[1], acc1, 0, 0, 0);
      acc0 = __builtin_amdgcn_mfma_f32_16x16x32_bf16(Al0, B[0], acc0, 0, 0, 0);
      acc1 = __builtin_amdgcn_mfma_f32_16x16x32_bf16(Al0, B[1], acc1, 0, 0, 0);
      acc0 = __builtin_amdgcn_mfma_f32_16x16x32_bf16(Ah0, B[4], acc0, 0, 0, 0);
      acc1 = __builtin_amdgcn_mfma_f32_16x16x32_bf16(Ah0, B[5], acc1, 0, 0, 0);
      acc0 = __builtin_amdgcn_mfma_f32_16x16x32_bf16(Ah1, B[2], acc0, 0, 0, 0);
      acc1 = __builtin_amdgcn_mfma_f32_16x16x32_bf16(Ah1, B[3], acc1, 0, 0, 0);
      acc0 = __builtin_amdgcn_mfma_f32_16x16x32_bf16(Al1, B[2], acc0, 0, 0, 0);
      acc1 = __builtin_amdgcn_mfma_f32_16x16x32_bf16(Al1, B[3], acc1, 0, 0, 0);
      acc0 = __builtin_amdgcn_mfma_f32_16x16x32_bf16(Ah1, B[6], acc0, 0, 0, 0);
      acc1 = __builtin_amdgcn_mfma_f32_16x16x32_bf16(Ah1, B[7], acc1, 0, 0, 0);
#pragma unroll
      for (int reg = 0; reg < 4; ++reg) {
        float s = fmaxf(acc0[reg], 0.f) * w30 + fmaxf(acc1[reg], 0.f) * w31;
        s = dpp_add16(s);                 // VALU-only 16-lane reduction
        if (n16 == 15)
          scores_s[task][wave * 128 + mt * 16 + g * 4 + reg] = s;
      }
    }
    ra0 = na0; rb0 = nb0; ra1 = na1; rb1 = nb1;
  }
  __syncthreads();

  // ---------- softmax over 512 robots, 2 tasks ----------
  const int lw = tid & 63, wid = tid >> 6;
  for (int task = 0; task < 2; ++task) {
    float s0 = scores_s[task][tid], s1 = scores_s[task][tid + 256];
    float mw = wred_max(fmaxf(s0, s1));
    if (lw == 0) red_a[wid] = mw;
    __syncthreads();
    float m = fmaxf(fmaxf(red_a[0], red_a[1]), fmaxf(red_a[2], red_a[3]));
    float e0 = expf(s0 - m), e1 = expf(s1 - m);
    float sw = wred_sum(e0 + e1);
    if (lw == 0) red_b[wid] = sw;
    __syncthreads();
    float inv = 1.f / (red_b[0] + red_b[1] + red_b[2] + red_b[3]);
    float* op = out + (size_t)(b * NT + t0 + task) * NR;
    op[tid]       = e0 * inv;
    op[256 + tid] = e1 * inv;
  }
}

// ---------------- launch ----------------
extern "C" void kernel_launch(void* const* d_in, const int* in_sizes, int n_in,
                              void* d_out, int out_size, void* d_ws, size_t ws_size,
                              hipStream_t stream)
{
  const float* rs   = (const float*)d_in[0];
  const float* ts   = (const float*)d_in[1];
  const float* r_w1 = (const float*)d_in[2];  const float* r_b1 = (const float*)d_in[3];
  const float* r_w2 = (const float*)d_in[4];  const float* r_b2 = (const float*)d_in[5];
  const float* t_w1 = (const float*)d_in[6];  const float* t_b1 = (const float*)d_in[7];
  const float* t_w2 = (const float*)d_in[8];  const float* t_b2 = (const float*)d_in[9];
  const float* wq   = (const float*)d_in[10]; const float* bq   = (const float*)d_in[11];
  const float* wk   = (const float*)d_in[12]; const float* bk   = (const float*)d_in[13];
  const float* wv   = (const float*)d_in[14]; const float* bv   = (const float*)d_in[15];
  const float* wo   = (const float*)d_in[16]; const float* bo   = (const float*)d_in[17];
  const float* a_w1 = (const float*)d_in[18]; const float* a_b1 = (const float*)d_in[19];
  const float* a_w2 = (const float*)d_in[20]; const float* a_b2 = (const float*)d_in[21];
  const float* a_w3 = (const float*)d_in[22]; const float* a_b3 = (const float*)d_in[23];

  float* wsf   = (float*)d_ws;
  float* kbuf  = wsf;                                   // 32*512*64
  float* vbuf  = kbuf  + (size_t)NB * NR * 64;          // 32*512*64
  float* rpbuf = vbuf  + (size_t)NB * NR * 64;          // 32*512*64
  float* qbuf  = rpbuf + (size_t)NB * NR * 64;          // 32*128*64
  unsigned short* w2f = (unsigned short*)(qbuf + (size_t)NB * NT * 64); // 8*64*8

  enc_kernel<<<dim3(641), dim3(256), 0, stream>>>(
      rs, ts, r_w1, r_b1, r_w2, r_b2, t_w1, t_b1, t_w2, t_b2,
      wq, bq, wk, bk, wv, bv, a_w1, a_w2, kbuf, vbuf, rpbuf, qbuf, w2f);

  attn_pair_kernel<<<dim3(2048), dim3(256), 0, stream>>>(
      qbuf, kbuf, vbuf, wo, bo, a_w1, a_b1, w2f, a_b2, a_w3, rpbuf,
      (float*)d_out);
}